// Round 1
// baseline (1360.782 us; speedup 1.0000x reference)
//
#include <hip/hip_runtime.h>
#include <hip/hip_bf16.h>
#include <math.h>

#define N_TOK 2048
#define H_DIM 768
#define E_NUM 64
#define I_DIM 256
#define TOPK 8
#define TM 32
#define CHUNK 128

// ---------------- Router: logits -> top-8 -> renormalized weights ----------
__global__ void router_kernel(const float* __restrict__ x, const float* __restrict__ rw,
                              int* __restrict__ topi, float* __restrict__ topw,
                              int* __restrict__ counts) {
  const int t = blockIdx.x;
  const int lane = threadIdx.x;  // 0..63, one wave
  __shared__ float xs[H_DIM];
  for (int h = lane; h < H_DIM; h += 64) xs[h] = x[t * H_DIM + h];
  __syncthreads();
  const float* wr = rw + (size_t)lane * H_DIM;
  float acc = 0.f;
  #pragma unroll 4
  for (int h = 0; h < H_DIM; h += 4) {
    float4 xv = *(const float4*)&xs[h];
    acc = fmaf(xv.x, wr[h + 0], acc);
    acc = fmaf(xv.y, wr[h + 1], acc);
    acc = fmaf(xv.z, wr[h + 2], acc);
    acc = fmaf(xv.w, wr[h + 3], acc);
  }
  float myv = acc;
  float topv[TOPK]; int topx[TOPK];
  #pragma unroll
  for (int k = 0; k < TOPK; ++k) {
    float bv = myv; int bi = lane;
    #pragma unroll
    for (int off = 32; off > 0; off >>= 1) {
      float ov = __shfl_xor(bv, off, 64);
      int oi = __shfl_xor(bi, off, 64);
      if (ov > bv || (ov == bv && oi < bi)) { bv = ov; bi = oi; }
    }
    topv[k] = bv; topx[k] = bi;
    if (lane == bi) myv = -INFINITY;
  }
  if (lane == 0) {
    // softmax over the top-8 logits == full softmax then renormalize (denominator cancels)
    float mx = topv[0];
    float w[TOPK];
    float s = 0.f;
    #pragma unroll
    for (int k = 0; k < TOPK; ++k) { w[k] = __expf(topv[k] - mx); s += w[k]; }
    float inv = 1.f / s;
    #pragma unroll
    for (int k = 0; k < TOPK; ++k) {
      topi[t * TOPK + k] = topx[k];
      topw[t * TOPK + k] = w[k] * inv;
      atomicAdd(&counts[topx[k]], 1);
    }
  }
}

// ---------------- Prefix sum over 64 expert counts -------------------------
__global__ void prefix_kernel(const int* __restrict__ counts,
                              int* __restrict__ offsets, int* __restrict__ cursor) {
  if (threadIdx.x == 0) {
    int s = 0;
    for (int e = 0; e < E_NUM; ++e) { offsets[e] = s; cursor[e] = s; s += counts[e]; }
    offsets[E_NUM] = s;
  }
}

// ---------------- Scatter (token,k) pairs into per-expert buckets ----------
__global__ void scatter_kernel(const int* __restrict__ topi, const float* __restrict__ topw,
                               int* __restrict__ cursor,
                               int* __restrict__ toklist, float* __restrict__ wlist) {
  int idx = blockIdx.x * 256 + threadIdx.x;  // (t,k) flat
  if (idx >= N_TOK * TOPK) return;
  int e = topi[idx];
  int pos = atomicAdd(&cursor[e], 1);
  toklist[pos] = idx >> 3;  // token id
  wlist[pos] = topw[idx];
}

// ---------------- Expert SwiGLU + down proj, expert-grouped tiles ----------
__global__ __launch_bounds__(256)
void expert_kernel(const float* __restrict__ x,
                   const float* __restrict__ wg, const float* __restrict__ wu,
                   const float* __restrict__ wd,
                   const int* __restrict__ offsets, const int* __restrict__ toklist,
                   const float* __restrict__ wlist, float* __restrict__ out) {
  const int e = blockIdx.y;
  const int start = offsets[e];
  const int cnt = offsets[e + 1] - start;
  const int t0 = blockIdx.x * TM;
  if (t0 >= cnt) return;
  const int tm = min(TM, cnt - t0);
  const int tid = threadIdx.x;  // 0..255

  __shared__ float smem[TM * I_DIM];  // 32 KB: x-chunks during gate/up, hmid after
  __shared__ int tk[TM];
  __shared__ float sw[TM];
  if (tid < TM) {
    int s = start + t0 + ((tid < tm) ? tid : 0);
    tk[tid] = toklist[s];
    sw[tid] = (tid < tm) ? wlist[s] : 0.f;
  }

  // ---- gate & up GEMV-batch: hmid_pre = x_tile @ wg, x_tile @ wu ----
  float accg[TM], accu[TM];
  #pragma unroll
  for (int t = 0; t < TM; ++t) { accg[t] = 0.f; accu[t] = 0.f; }
  const int i = tid;  // intermediate column, I_DIM == blockDim
  const float* wgp = wg + (size_t)e * H_DIM * I_DIM + i;
  const float* wup = wu + (size_t)e * H_DIM * I_DIM + i;

  for (int kc = 0; kc < H_DIM; kc += CHUNK) {
    __syncthreads();  // protect previous chunk reads
    for (int idx = tid; idx < TM * CHUNK; idx += 256) {
      int t = idx >> 7, hh = idx & (CHUNK - 1);
      smem[idx] = (t < tm) ? x[(size_t)tk[t] * H_DIM + kc + hh] : 0.f;
    }
    __syncthreads();
    for (int h = 0; h < CHUNK; h += 4) {
      float g0 = wgp[(size_t)(kc + h + 0) * I_DIM];
      float g1 = wgp[(size_t)(kc + h + 1) * I_DIM];
      float g2 = wgp[(size_t)(kc + h + 2) * I_DIM];
      float g3 = wgp[(size_t)(kc + h + 3) * I_DIM];
      float u0 = wup[(size_t)(kc + h + 0) * I_DIM];
      float u1 = wup[(size_t)(kc + h + 1) * I_DIM];
      float u2 = wup[(size_t)(kc + h + 2) * I_DIM];
      float u3 = wup[(size_t)(kc + h + 3) * I_DIM];
      #pragma unroll
      for (int t = 0; t < TM; ++t) {
        const float4 xv = *(const float4*)&smem[t * CHUNK + h];
        accg[t] = fmaf(xv.x, g0, accg[t]);
        accg[t] = fmaf(xv.y, g1, accg[t]);
        accg[t] = fmaf(xv.z, g2, accg[t]);
        accg[t] = fmaf(xv.w, g3, accg[t]);
        accu[t] = fmaf(xv.x, u0, accu[t]);
        accu[t] = fmaf(xv.y, u1, accu[t]);
        accu[t] = fmaf(xv.z, u2, accu[t]);
        accu[t] = fmaf(xv.w, u3, accu[t]);
      }
    }
  }

  __syncthreads();
  // ---- SwiGLU -> hmid in LDS ----
  #pragma unroll
  for (int t = 0; t < TM; ++t) {
    float g = accg[t];
    float sig = 1.f / (1.f + __expf(-g));
    smem[t * I_DIM + i] = g * sig * accu[t];
  }
  __syncthreads();

  // ---- down proj: out_tile = hmid @ wd, weighted atomic accumulate ----
  float acc[3][TM];
  #pragma unroll
  for (int c = 0; c < 3; ++c)
    #pragma unroll
    for (int t = 0; t < TM; ++t) acc[c][t] = 0.f;
  const float* wdp = wd + (size_t)e * I_DIM * H_DIM;
  for (int ii = 0; ii < I_DIM; ii += 4) {
    float d[3][4];
    #pragma unroll
    for (int c = 0; c < 3; ++c)
      #pragma unroll
      for (int j = 0; j < 4; ++j)
        d[c][j] = wdp[(size_t)(ii + j) * H_DIM + c * 256 + tid];
    #pragma unroll
    for (int t = 0; t < TM; ++t) {
      const float4 hv = *(const float4*)&smem[t * I_DIM + ii];
      #pragma unroll
      for (int c = 0; c < 3; ++c) {
        acc[c][t] = fmaf(hv.x, d[c][0], acc[c][t]);
        acc[c][t] = fmaf(hv.y, d[c][1], acc[c][t]);
        acc[c][t] = fmaf(hv.z, d[c][2], acc[c][t]);
        acc[c][t] = fmaf(hv.w, d[c][3], acc[c][t]);
      }
    }
  }
  #pragma unroll
  for (int c = 0; c < 3; ++c) {
    for (int t = 0; t < tm; ++t) {
      atomicAdd(&out[(size_t)tk[t] * H_DIM + c * 256 + tid], sw[t] * acc[c][t]);
    }
  }
}

extern "C" void kernel_launch(void* const* d_in, const int* in_sizes, int n_in,
                              void* d_out, int out_size, void* d_ws, size_t ws_size,
                              hipStream_t stream) {
  const float* x  = (const float*)d_in[0];
  const float* rw = (const float*)d_in[1];
  const float* wg = (const float*)d_in[2];
  const float* wu = (const float*)d_in[3];
  const float* wd = (const float*)d_in[4];
  float* out = (float*)d_out;

  char* ws = (char*)d_ws;
  int*   topi    = (int*)(ws + 0);         // 2048*8 ints
  float* topw    = (float*)(ws + 65536);   // 2048*8 floats
  int*   counts  = (int*)(ws + 131072);    // 64 ints
  int*   offsets = (int*)(ws + 131584);    // 65 ints
  int*   cursor  = (int*)(ws + 132096);    // 64 ints
  int*   toklist = (int*)(ws + 132608);    // 2048*8 ints
  float* wlist   = (float*)(ws + 198144);  // 2048*8 floats

  hipMemsetAsync(counts, 0, E_NUM * sizeof(int), stream);
  hipMemsetAsync(d_out, 0, (size_t)out_size * sizeof(float), stream);

  router_kernel<<<N_TOK, 64, 0, stream>>>(x, rw, topi, topw, counts);
  prefix_kernel<<<1, 64, 0, stream>>>(counts, offsets, cursor);
  scatter_kernel<<<(N_TOK * TOPK + 255) / 256, 256, 0, stream>>>(topi, topw, cursor, toklist, wlist);
  expert_kernel<<<dim3(64, E_NUM), 256, 0, stream>>>(x, wg, wu, wd, offsets, toklist, wlist, out);
}

// Round 2
// 302.882 us; speedup vs baseline: 4.4928x; 4.4928x over previous
//
#include <hip/hip_runtime.h>
#include <hip/hip_bf16.h>
#include <math.h>

#define N_TOK 2048
#define H_DIM 768
#define E_NUM 64
#define I_DIM 256
#define TOPK 8
#define NPAIR (N_TOK * TOPK)

typedef __attribute__((ext_vector_type(8))) short short8;
typedef __attribute__((ext_vector_type(4))) float f32x4;

__device__ inline ushort f2bf(float f) {
  unsigned u = __builtin_bit_cast(unsigned, f);
  u += 0x7fffu + ((u >> 16) & 1u);
  return (ushort)(u >> 16);
}

__device__ inline f32x4 mfma16(short8 a, short8 b, f32x4 c) {
  return __builtin_amdgcn_mfma_f32_16x16x32_bf16(a, b, c, 0, 0, 0);
}

// ---------------- x fp32 -> bf16 ----------------
__global__ __launch_bounds__(512) void cvt_x_kernel(const float* __restrict__ x,
                                                    ushort* __restrict__ xbf) {
  const int i = blockIdx.x * 512 + threadIdx.x;  // 8 floats per thread
  const float* s = x + (size_t)i * 8;
  short8 r;
  #pragma unroll
  for (int j = 0; j < 8; ++j) r[j] = (short)f2bf(s[j]);
  *(short8*)(xbf + (size_t)i * 8) = r;
}

// ---------------- Router: 32 tokens/block, logits->top8->renorm ------------
__global__ __launch_bounds__(512) void router2_kernel(const float* __restrict__ x,
                                                      const float* __restrict__ rw,
                                                      int* __restrict__ topi,
                                                      float* __restrict__ topw,
                                                      int* __restrict__ counts) {
  const int t0 = blockIdx.x * 32;
  __shared__ float xs[32][772];
  __shared__ float lg[32][68];
  const int tid = threadIdx.x;
  #pragma unroll
  for (int j = 0; j < 12; ++j) {
    int fid = tid + j * 512;
    int row = fid / 192, c4 = (fid % 192) * 4;
    *(float4*)&xs[row][c4] = *(const float4*)&x[(size_t)(t0 + row) * H_DIM + c4];
  }
  __syncthreads();
  {
    const int tok = tid & 31, eg = tid >> 5;  // eg 0..15 -> 4 experts each
    const float* w0 = rw + (size_t)(eg * 4 + 0) * H_DIM;
    const float* w1 = w0 + H_DIM;
    const float* w2 = w1 + H_DIM;
    const float* w3 = w2 + H_DIM;
    float a0 = 0.f, a1 = 0.f, a2 = 0.f, a3 = 0.f;
    for (int h = 0; h < H_DIM; h += 4) {
      float4 xv = *(float4*)&xs[tok][h];
      float4 b0 = *(const float4*)&w0[h];
      float4 b1 = *(const float4*)&w1[h];
      float4 b2 = *(const float4*)&w2[h];
      float4 b3 = *(const float4*)&w3[h];
      a0 = fmaf(xv.x, b0.x, fmaf(xv.y, b0.y, fmaf(xv.z, b0.z, fmaf(xv.w, b0.w, a0))));
      a1 = fmaf(xv.x, b1.x, fmaf(xv.y, b1.y, fmaf(xv.z, b1.z, fmaf(xv.w, b1.w, a1))));
      a2 = fmaf(xv.x, b2.x, fmaf(xv.y, b2.y, fmaf(xv.z, b2.z, fmaf(xv.w, b2.w, a2))));
      a3 = fmaf(xv.x, b3.x, fmaf(xv.y, b3.y, fmaf(xv.z, b3.z, fmaf(xv.w, b3.w, a3))));
    }
    lg[tok][eg * 4 + 0] = a0;
    lg[tok][eg * 4 + 1] = a1;
    lg[tok][eg * 4 + 2] = a2;
    lg[tok][eg * 4 + 3] = a3;
  }
  __syncthreads();
  const int wid = tid >> 6, l = tid & 63;
  for (int q = 0; q < 4; ++q) {
    const int tk = wid * 4 + q;
    float myv = lg[tk][l];
    float topv[TOPK]; int topx[TOPK];
    #pragma unroll
    for (int k = 0; k < TOPK; ++k) {
      float bv = myv; int bi = l;
      #pragma unroll
      for (int off = 32; off > 0; off >>= 1) {
        float ov = __shfl_xor(bv, off, 64);
        int oi = __shfl_xor(bi, off, 64);
        if (ov > bv || (ov == bv && oi < bi)) { bv = ov; bi = oi; }
      }
      topv[k] = bv; topx[k] = bi;
      if (l == bi) myv = -INFINITY;
    }
    if (l == 0) {
      float mx = topv[0], w[TOPK], s = 0.f;
      #pragma unroll
      for (int k = 0; k < TOPK; ++k) { w[k] = __expf(topv[k] - mx); s += w[k]; }
      float inv = 1.f / s;
      #pragma unroll
      for (int k = 0; k < TOPK; ++k) {
        topi[(t0 + tk) * TOPK + k] = topx[k];
        topw[(t0 + tk) * TOPK + k] = w[k] * inv;
        atomicAdd(&counts[topx[k]], 1);
      }
    }
  }
}

// ---------------- Prefix sum over expert counts ----------------------------
__global__ void prefix_kernel(const int* __restrict__ counts,
                              int* __restrict__ offsets, int* __restrict__ cursor) {
  if (threadIdx.x == 0) {
    int s = 0;
    for (int e = 0; e < E_NUM; ++e) { offsets[e] = s; cursor[e] = s; s += counts[e]; }
    offsets[E_NUM] = s;
  }
}

// ---------------- Scatter (token,k) pairs into per-expert buckets ----------
__global__ void scatter_kernel(const int* __restrict__ topi, const float* __restrict__ topw,
                               int* __restrict__ cursor,
                               int* __restrict__ toklist, float* __restrict__ wlist) {
  int idx = blockIdx.x * 256 + threadIdx.x;
  if (idx >= NPAIR) return;
  int e = topi[idx];
  int pos = atomicAdd(&cursor[e], 1);
  toklist[pos] = idx >> 3;
  wlist[pos] = topw[idx];
}

// ---------------- K1: gate/up MFMA + SwiGLU -> hmid (bf16, pair-ordered) ---
// block = (i-block of 32 cols, expert, token-block of 384)
#define K1_TB 384
__global__ __launch_bounds__(512) void k1_gateup(const ushort* __restrict__ xbf,
                                                 const float* __restrict__ wg,
                                                 const float* __restrict__ wu,
                                                 const int* __restrict__ offsets,
                                                 const int* __restrict__ toklist,
                                                 ushort* __restrict__ hmid) {
  const int e = blockIdx.y, ib = blockIdx.x;
  const int i0 = ib * 32;
  const int start = offsets[e], cnt = offsets[e + 1] - start;
  const int tokbase = blockIdx.z * K1_TB;
  if (tokbase >= cnt) return;
  const int cntb = min(K1_TB, cnt - tokbase);
  const int ntiles = (cntb + 127) >> 7;

  __shared__ ushort Bs[64][392];      // padded col-major: [col][k], 64 gate+up cols
  __shared__ float gbuf[4][32 * 32];
  __shared__ ushort hbuf[128 * 32];
  __shared__ int tks[K1_TB];

  const int tid = threadIdx.x;
  for (int r = tid; r < K1_TB; r += 512)
    tks[r] = toklist[start + tokbase + min(r, cntb - 1)];

  const int l = tid & 63, wid = tid >> 6;
  const int tf = wid & 3, gu = wid >> 2;
  // staging role
  const int c = tid & 63, kb = tid >> 6;
  const float* wsrc = (c < 32 ? wg : wu) + (size_t)e * H_DIM * I_DIM + i0 + (c & 31);

  f32x4 acc[3][2][2] = {};

  for (int kh = 0; kh < H_DIM; kh += 384) {
    __syncthreads();
    // stage B: 64 cols x 384 k (each thread: col c, k-band kb*48..+47)
    #pragma unroll
    for (int q = 0; q < 6; ++q) {
      const int k = kb * 48 + q * 8;
      short8 r;
      #pragma unroll
      for (int j = 0; j < 8; ++j)
        r[j] = (short)f2bf(wsrc[(size_t)(kh + k + j) * I_DIM]);
      *(short8*)&Bs[c][k] = r;
    }
    __syncthreads();
    const int ko = (l >> 4) * 8;
    #pragma unroll
    for (int tile = 0; tile < 3; ++tile) {
      if (tile < ntiles) {
        const ushort* ap0 = xbf + (size_t)tks[tile * 128 + tf * 32 + (l & 15)] * H_DIM + kh;
        const ushort* ap1 = xbf + (size_t)tks[tile * 128 + tf * 32 + 16 + (l & 15)] * H_DIM + kh;
        #pragma unroll
        for (int ks = 0; ks < 12; ++ks) {
          short8 a0 = *(const short8*)(ap0 + ks * 32 + ko);
          short8 a1 = *(const short8*)(ap1 + ks * 32 + ko);
          short8 b0 = *(const short8*)&Bs[gu * 32 + (l & 15)][ks * 32 + ko];
          short8 b1 = *(const short8*)&Bs[gu * 32 + 16 + (l & 15)][ks * 32 + ko];
          acc[tile][0][0] = mfma16(a0, b0, acc[tile][0][0]);
          acc[tile][1][0] = mfma16(a1, b0, acc[tile][1][0]);
          acc[tile][0][1] = mfma16(a0, b1, acc[tile][0][1]);
          acc[tile][1][1] = mfma16(a1, b1, acc[tile][1][1]);
        }
      }
    }
  }

  // epilogue: SwiGLU exchange gate<->up waves, then store hmid
  const int rgrp = l >> 4, col_l = l & 15;
  #pragma unroll
  for (int tile = 0; tile < 3; ++tile) {
    if (tile >= ntiles) break;
    const int tm = min(128, cntb - tile * 128);
    __syncthreads();
    if (gu == 0) {
      #pragma unroll
      for (int tr = 0; tr < 2; ++tr)
        #pragma unroll
        for (int cf = 0; cf < 2; ++cf)
          #pragma unroll
          for (int j = 0; j < 4; ++j) {
            int row = tr * 16 + rgrp * 4 + j, col = cf * 16 + col_l;
            gbuf[tf][row * 32 + col] = acc[tile][tr][cf][j];
          }
    }
    __syncthreads();
    if (gu == 1) {
      #pragma unroll
      for (int tr = 0; tr < 2; ++tr)
        #pragma unroll
        for (int cf = 0; cf < 2; ++cf)
          #pragma unroll
          for (int j = 0; j < 4; ++j) {
            int row = tr * 16 + rgrp * 4 + j, col = cf * 16 + col_l;
            float g = gbuf[tf][row * 32 + col];
            float hm = g / (1.f + __expf(-g)) * acc[tile][tr][cf][j];
            hbuf[(tf * 32 + row) * 32 + col] = f2bf(hm);
          }
    }
    __syncthreads();
    {
      const int row = tid >> 2, part = tid & 3;
      if (row < tm) {
        ushort* dst = hmid + (size_t)(start + tokbase + tile * 128 + row) * I_DIM + i0 + part * 8;
        *(short8*)dst = *(const short8*)&hbuf[row * 32 + part * 8];
      }
    }
  }
}

// ---------------- K2: down-proj MFMA, weighted atomic accumulate -----------
// block = (h-slice of 192, expert, token-block of 128)
__global__ __launch_bounds__(512) void k2_down(const ushort* __restrict__ hmid,
                                               const float* __restrict__ wd,
                                               const int* __restrict__ offsets,
                                               const int* __restrict__ toklist,
                                               const float* __restrict__ wlist,
                                               float* __restrict__ out) {
  const int e = blockIdx.y, hs = blockIdx.x;
  const int h0 = hs * 192;
  const int start = offsets[e], cnt = offsets[e + 1] - start;
  const int tokbase = blockIdx.z * 128;
  if (tokbase >= cnt) return;
  const int tm = min(128, cnt - tokbase);

  __shared__ ushort Ds[192][136];  // padded col-major [col][k]
  __shared__ float sws[128];
  __shared__ int tks[128];

  const int tid = threadIdx.x;
  if (tid < 128) {
    int p = start + tokbase + min(tid, tm - 1);
    sws[tid] = (tid < tm) ? wlist[p] : 0.f;
    tks[tid] = toklist[p];
  }

  const int l = tid & 63, wid = tid >> 6;
  const int tf = wid & 3, ch = wid >> 2;
  f32x4 acc[2][6] = {};

  const int p0 = min(start + tokbase + tf * 32 + (l & 15), NPAIR - 1);
  const int p1 = min(start + tokbase + tf * 32 + 16 + (l & 15), NPAIR - 1);
  const int ko = (l >> 4) * 8;

  for (int kh = 0; kh < I_DIM; kh += 128) {
    __syncthreads();
    #pragma unroll
    for (int it = 0; it < 6; ++it) {
      int idx = tid + it * 512;
      int cc = idx % 192, kq = idx / 192;  // kq 0..15
      const float* src = wd + (size_t)e * I_DIM * H_DIM + (size_t)(kh + kq * 8) * H_DIM + h0 + cc;
      short8 r;
      #pragma unroll
      for (int j = 0; j < 8; ++j) r[j] = (short)f2bf(src[(size_t)j * H_DIM]);
      *(short8*)&Ds[cc][kq * 8] = r;
    }
    __syncthreads();
    const ushort* ap0 = hmid + (size_t)p0 * I_DIM + kh;
    const ushort* ap1 = hmid + (size_t)p1 * I_DIM + kh;
    #pragma unroll
    for (int ks = 0; ks < 4; ++ks) {
      short8 a0 = *(const short8*)(ap0 + ks * 32 + ko);
      short8 a1 = *(const short8*)(ap1 + ks * 32 + ko);
      #pragma unroll
      for (int cf = 0; cf < 6; ++cf) {
        short8 b = *(const short8*)&Ds[ch * 96 + cf * 16 + (l & 15)][ks * 32 + ko];
        acc[0][cf] = mfma16(a0, b, acc[0][cf]);
        acc[1][cf] = mfma16(a1, b, acc[1][cf]);
      }
    }
  }

  const int rgrp = l >> 4, col_l = l & 15;
  #pragma unroll
  for (int tr = 0; tr < 2; ++tr)
    #pragma unroll
    for (int j = 0; j < 4; ++j) {
      int r = tf * 32 + tr * 16 + rgrp * 4 + j;
      if (r < tm) {
        float w = sws[r];
        int trow = tks[r];
        #pragma unroll
        for (int cf = 0; cf < 6; ++cf) {
          int hcol = h0 + ch * 96 + cf * 16 + col_l;
          atomicAdd(&out[(size_t)trow * H_DIM + hcol], acc[tr][cf][j] * w);
        }
      }
    }
}

extern "C" void kernel_launch(void* const* d_in, const int* in_sizes, int n_in,
                              void* d_out, int out_size, void* d_ws, size_t ws_size,
                              hipStream_t stream) {
  const float* x  = (const float*)d_in[0];
  const float* rw = (const float*)d_in[1];
  const float* wg = (const float*)d_in[2];
  const float* wu = (const float*)d_in[3];
  const float* wd = (const float*)d_in[4];
  float* out = (float*)d_out;

  char* ws = (char*)d_ws;
  int*    topi    = (int*)(ws + 0);          // 16384 ints
  float*  topw    = (float*)(ws + 65536);    // 16384 floats
  int*    counts  = (int*)(ws + 131072);
  int*    offsets = (int*)(ws + 131584);
  int*    cursor  = (int*)(ws + 132096);
  int*    toklist = (int*)(ws + 132608);     // 16384 ints
  float*  wlist   = (float*)(ws + 198144);   // 16384 floats
  ushort* xbf     = (ushort*)(ws + 264192);  // 2048*768 bf16 = 3 MB
  ushort* hmid    = (ushort*)(ws + 3409920); // 16384*256 bf16 = 8 MB  (end ~11.3 MB)

  hipMemsetAsync(counts, 0, E_NUM * sizeof(int), stream);
  hipMemsetAsync(d_out, 0, (size_t)out_size * sizeof(float), stream);

  cvt_x_kernel<<<(N_TOK * H_DIM / 8) / 512, 512, 0, stream>>>(x, xbf);
  router2_kernel<<<N_TOK / 32, 512, 0, stream>>>(x, rw, topi, topw, counts);
  prefix_kernel<<<1, 64, 0, stream>>>(counts, offsets, cursor);
  scatter_kernel<<<(NPAIR + 255) / 256, 256, 0, stream>>>(topi, topw, cursor, toklist, wlist);
  k1_gateup<<<dim3(8, E_NUM, (N_TOK + K1_TB - 1) / K1_TB), 512, 0, stream>>>(
      xbf, wg, wu, offsets, toklist, hmid);
  k2_down<<<dim3(4, E_NUM, N_TOK / 128), 512, 0, stream>>>(
      hmid, wd, offsets, toklist, wlist, out);
}

// Round 3
// 277.094 us; speedup vs baseline: 4.9109x; 1.0931x over previous
//
#include <hip/hip_runtime.h>
#include <hip/hip_bf16.h>
#include <math.h>

#define N_TOK 2048
#define H_DIM 768
#define E_NUM 64
#define I_DIM 256
#define TOPK 8
#define NPAIR (N_TOK * TOPK)

typedef __attribute__((ext_vector_type(8))) short short8;
typedef __attribute__((ext_vector_type(4))) float f32x4;

__device__ inline ushort f2bf(float f) {
  unsigned u = __builtin_bit_cast(unsigned, f);
  u += 0x7fffu + ((u >> 16) & 1u);
  return (ushort)(u >> 16);
}

__device__ inline f32x4 mfma16(short8 a, short8 b, f32x4 c) {
  return __builtin_amdgcn_mfma_f32_16x16x32_bf16(a, b, c, 0, 0, 0);
}

// ---------------- x fp32 -> bf16 ----------------
__global__ __launch_bounds__(512) void cvt_x_kernel(const float* __restrict__ x,
                                                    ushort* __restrict__ xbf) {
  const int i = blockIdx.x * 512 + threadIdx.x;  // 8 floats per thread
  const float* s = x + (size_t)i * 8;
  short8 r;
  #pragma unroll
  for (int j = 0; j < 8; ++j) r[j] = (short)f2bf(s[j]);
  *(short8*)(xbf + (size_t)i * 8) = r;
}

// ---------------- Router GEMM (fp32, split-K): part[ks][t][e] --------------
// grid (32 token-tiles, 3 k-splits), 256 threads, 4x4 register blocking
#define RT_KC 256
__global__ __launch_bounds__(256) void router_gemm(const float* __restrict__ x,
                                                   const float* __restrict__ rw,
                                                   float* __restrict__ part) {
  const int t0 = blockIdx.x * 64, k0 = blockIdx.y * RT_KC;
  __shared__ float xs[64][68];
  __shared__ float ws[64][68];
  const int tid = threadIdx.x;
  const int tx = tid & 15, ty = tid >> 4;
  float acc[4][4] = {};
  for (int kc = 0; kc < RT_KC; kc += 64) {
    __syncthreads();
    {
      const int r = tid >> 2, q = tid & 3;
      const float4* srcx = (const float4*)&x[(size_t)(t0 + r) * H_DIM + k0 + kc];
      const float4* srcw = (const float4*)&rw[(size_t)r * H_DIM + k0 + kc];
      float4* dstx = (float4*)&xs[r][0];
      float4* dstw = (float4*)&ws[r][0];
      #pragma unroll
      for (int j = 0; j < 4; ++j) {
        dstx[q * 4 + j] = srcx[q * 4 + j];
        dstw[q * 4 + j] = srcw[q * 4 + j];
      }
    }
    __syncthreads();
    #pragma unroll
    for (int k4 = 0; k4 < 16; ++k4) {
      float4 a0 = *(float4*)&xs[ty * 4 + 0][k4 * 4];
      float4 a1 = *(float4*)&xs[ty * 4 + 1][k4 * 4];
      float4 a2 = *(float4*)&xs[ty * 4 + 2][k4 * 4];
      float4 a3 = *(float4*)&xs[ty * 4 + 3][k4 * 4];
      float4 b0 = *(float4*)&ws[tx * 4 + 0][k4 * 4];
      float4 b1 = *(float4*)&ws[tx * 4 + 1][k4 * 4];
      float4 b2 = *(float4*)&ws[tx * 4 + 2][k4 * 4];
      float4 b3 = *(float4*)&ws[tx * 4 + 3][k4 * 4];
      #define RFMA(i, j, av, bv) \
        acc[i][j] = fmaf(av.x, bv.x, fmaf(av.y, bv.y, fmaf(av.z, bv.z, fmaf(av.w, bv.w, acc[i][j]))))
      RFMA(0, 0, a0, b0); RFMA(0, 1, a0, b1); RFMA(0, 2, a0, b2); RFMA(0, 3, a0, b3);
      RFMA(1, 0, a1, b0); RFMA(1, 1, a1, b1); RFMA(1, 2, a1, b2); RFMA(1, 3, a1, b3);
      RFMA(2, 0, a2, b0); RFMA(2, 1, a2, b1); RFMA(2, 2, a2, b2); RFMA(2, 3, a2, b3);
      RFMA(3, 0, a3, b0); RFMA(3, 1, a3, b1); RFMA(3, 2, a3, b2); RFMA(3, 3, a3, b3);
      #undef RFMA
    }
  }
  float* pp = part + ((size_t)blockIdx.y * N_TOK + t0) * E_NUM;
  #pragma unroll
  for (int i = 0; i < 4; ++i)
    #pragma unroll
    for (int j = 0; j < 4; ++j)
      pp[(ty * 4 + i) * E_NUM + tx * 4 + j] = acc[i][j];
}

// ---------------- Router top-k: sum partials -> top8 -> renorm -------------
__global__ __launch_bounds__(256) void router_topk(const float* __restrict__ part,
                                                   int* __restrict__ topi,
                                                   float* __restrict__ topw,
                                                   int* __restrict__ counts) {
  const int t = blockIdx.x * 4 + (threadIdx.x >> 6);
  const int l = threadIdx.x & 63;
  float myv = part[(size_t)t * E_NUM + l] +
              part[((size_t)N_TOK + t) * E_NUM + l] +
              part[((size_t)2 * N_TOK + t) * E_NUM + l];
  float topv[TOPK]; int topx[TOPK];
  #pragma unroll
  for (int k = 0; k < TOPK; ++k) {
    float bv = myv; int bi = l;
    #pragma unroll
    for (int off = 32; off > 0; off >>= 1) {
      float ov = __shfl_xor(bv, off, 64);
      int oi = __shfl_xor(bi, off, 64);
      if (ov > bv || (ov == bv && oi < bi)) { bv = ov; bi = oi; }
    }
    topv[k] = bv; topx[k] = bi;
    if (l == bi) myv = -INFINITY;
  }
  if (l == 0) {
    float mx = topv[0], w[TOPK], s = 0.f;
    #pragma unroll
    for (int k = 0; k < TOPK; ++k) { w[k] = __expf(topv[k] - mx); s += w[k]; }
    float inv = 1.f / s;
    #pragma unroll
    for (int k = 0; k < TOPK; ++k) {
      topi[t * TOPK + k] = topx[k];
      topw[t * TOPK + k] = w[k] * inv;
      atomicAdd(&counts[topx[k]], 1);
    }
  }
}

// ---------------- Prefix sum over expert counts ----------------------------
__global__ void prefix_kernel(const int* __restrict__ counts,
                              int* __restrict__ offsets, int* __restrict__ cursor) {
  if (threadIdx.x == 0) {
    int s = 0;
    for (int e = 0; e < E_NUM; ++e) { offsets[e] = s; cursor[e] = s; s += counts[e]; }
    offsets[E_NUM] = s;
  }
}

// ---------------- Scatter (token,k) pairs into per-expert buckets ----------
__global__ void scatter_kernel(const int* __restrict__ topi, const float* __restrict__ topw,
                               int* __restrict__ cursor,
                               int* __restrict__ toklist, float* __restrict__ wlist) {
  int idx = blockIdx.x * 256 + threadIdx.x;
  if (idx >= NPAIR) return;
  int e = topi[idx];
  int pos = atomicAdd(&cursor[e], 1);
  toklist[pos] = idx >> 3;
  wlist[pos] = topw[idx];
}

// ---------------- K1: gate/up MFMA + SwiGLU -> hmid (bf16, pair-ordered) ---
// block = (i-block of 32 cols, expert, token-block of 384)
#define K1_TB 384
__global__ __launch_bounds__(512) void k1_gateup(const ushort* __restrict__ xbf,
                                                 const float* __restrict__ wg,
                                                 const float* __restrict__ wu,
                                                 const int* __restrict__ offsets,
                                                 const int* __restrict__ toklist,
                                                 ushort* __restrict__ hmid) {
  const int e = blockIdx.y, ib = blockIdx.x;
  const int i0 = ib * 32;
  const int start = offsets[e], cnt = offsets[e + 1] - start;
  const int tokbase = blockIdx.z * K1_TB;
  if (tokbase >= cnt) return;
  const int cntb = min(K1_TB, cnt - tokbase);
  const int ntiles = (cntb + 127) >> 7;

  __shared__ ushort Bs[64][392];      // padded col-major: [col][k], 64 gate+up cols
  __shared__ float gbuf[4][32 * 32];
  __shared__ ushort hbuf[128 * 32];
  __shared__ int tks[K1_TB];

  const int tid = threadIdx.x;
  for (int r = tid; r < K1_TB; r += 512)
    tks[r] = toklist[start + tokbase + min(r, cntb - 1)];

  const int l = tid & 63, wid = tid >> 6;
  const int tf = wid & 3, gu = wid >> 2;
  // staging role
  const int c = tid & 63, kb = tid >> 6;
  const float* wsrc = (c < 32 ? wg : wu) + (size_t)e * H_DIM * I_DIM + i0 + (c & 31);

  f32x4 acc[3][2][2] = {};

  for (int kh = 0; kh < H_DIM; kh += 384) {
    __syncthreads();
    // stage B: 64 cols x 384 k (each thread: col c, k-band kb*48..+47)
    #pragma unroll
    for (int q = 0; q < 6; ++q) {
      const int k = kb * 48 + q * 8;
      short8 r;
      #pragma unroll
      for (int j = 0; j < 8; ++j)
        r[j] = (short)f2bf(wsrc[(size_t)(kh + k + j) * I_DIM]);
      *(short8*)&Bs[c][k] = r;
    }
    __syncthreads();
    const int ko = (l >> 4) * 8;
    #pragma unroll
    for (int tile = 0; tile < 3; ++tile) {
      if (tile < ntiles) {
        const ushort* ap0 = xbf + (size_t)tks[tile * 128 + tf * 32 + (l & 15)] * H_DIM + kh;
        const ushort* ap1 = xbf + (size_t)tks[tile * 128 + tf * 32 + 16 + (l & 15)] * H_DIM + kh;
        #pragma unroll
        for (int ks = 0; ks < 12; ++ks) {
          short8 a0 = *(const short8*)(ap0 + ks * 32 + ko);
          short8 a1 = *(const short8*)(ap1 + ks * 32 + ko);
          short8 b0 = *(const short8*)&Bs[gu * 32 + (l & 15)][ks * 32 + ko];
          short8 b1 = *(const short8*)&Bs[gu * 32 + 16 + (l & 15)][ks * 32 + ko];
          acc[tile][0][0] = mfma16(a0, b0, acc[tile][0][0]);
          acc[tile][1][0] = mfma16(a1, b0, acc[tile][1][0]);
          acc[tile][0][1] = mfma16(a0, b1, acc[tile][0][1]);
          acc[tile][1][1] = mfma16(a1, b1, acc[tile][1][1]);
        }
      }
    }
  }

  // epilogue: SwiGLU exchange gate<->up waves, then store hmid
  const int rgrp = l >> 4, col_l = l & 15;
  #pragma unroll
  for (int tile = 0; tile < 3; ++tile) {
    if (tile >= ntiles) break;
    const int tm = min(128, cntb - tile * 128);
    __syncthreads();
    if (gu == 0) {
      #pragma unroll
      for (int tr = 0; tr < 2; ++tr)
        #pragma unroll
        for (int cf = 0; cf < 2; ++cf)
          #pragma unroll
          for (int j = 0; j < 4; ++j) {
            int row = tr * 16 + rgrp * 4 + j, col = cf * 16 + col_l;
            gbuf[tf][row * 32 + col] = acc[tile][tr][cf][j];
          }
    }
    __syncthreads();
    if (gu == 1) {
      #pragma unroll
      for (int tr = 0; tr < 2; ++tr)
        #pragma unroll
        for (int cf = 0; cf < 2; ++cf)
          #pragma unroll
          for (int j = 0; j < 4; ++j) {
            int row = tr * 16 + rgrp * 4 + j, col = cf * 16 + col_l;
            float g = gbuf[tf][row * 32 + col];
            float hm = g / (1.f + __expf(-g)) * acc[tile][tr][cf][j];
            hbuf[(tf * 32 + row) * 32 + col] = f2bf(hm);
          }
    }
    __syncthreads();
    {
      const int row = tid >> 2, part = tid & 3;
      if (row < tm) {
        ushort* dst = hmid + (size_t)(start + tokbase + tile * 128 + row) * I_DIM + i0 + part * 8;
        *(short8*)dst = *(const short8*)&hbuf[row * 32 + part * 8];
      }
    }
  }
}

// ---------------- K2: down-proj MFMA, weighted atomic accumulate -----------
// block = (h-slice of 192, expert, token-block of 128)
__global__ __launch_bounds__(512) void k2_down(const ushort* __restrict__ hmid,
                                               const float* __restrict__ wd,
                                               const int* __restrict__ offsets,
                                               const int* __restrict__ toklist,
                                               const float* __restrict__ wlist,
                                               float* __restrict__ out) {
  const int e = blockIdx.y, hs = blockIdx.x;
  const int h0 = hs * 192;
  const int start = offsets[e], cnt = offsets[e + 1] - start;
  const int tokbase = blockIdx.z * 128;
  if (tokbase >= cnt) return;
  const int tm = min(128, cnt - tokbase);

  __shared__ ushort Ds[192][136];  // padded col-major [col][k]
  __shared__ float sws[128];
  __shared__ int tks[128];

  const int tid = threadIdx.x;
  if (tid < 128) {
    int p = start + tokbase + min(tid, tm - 1);
    sws[tid] = (tid < tm) ? wlist[p] : 0.f;
    tks[tid] = toklist[p];
  }

  const int l = tid & 63, wid = tid >> 6;
  const int tf = wid & 3, ch = wid >> 2;
  f32x4 acc[2][6] = {};

  const int p0 = min(start + tokbase + tf * 32 + (l & 15), NPAIR - 1);
  const int p1 = min(start + tokbase + tf * 32 + 16 + (l & 15), NPAIR - 1);
  const int ko = (l >> 4) * 8;

  for (int kh = 0; kh < I_DIM; kh += 128) {
    __syncthreads();
    #pragma unroll
    for (int it = 0; it < 6; ++it) {
      int idx = tid + it * 512;
      int cc = idx % 192, kq = idx / 192;  // kq 0..15
      const float* src = wd + (size_t)e * I_DIM * H_DIM + (size_t)(kh + kq * 8) * H_DIM + h0 + cc;
      short8 r;
      #pragma unroll
      for (int j = 0; j < 8; ++j) r[j] = (short)f2bf(src[(size_t)j * H_DIM]);
      *(short8*)&Ds[cc][kq * 8] = r;
    }
    __syncthreads();
    const ushort* ap0 = hmid + (size_t)p0 * I_DIM + kh;
    const ushort* ap1 = hmid + (size_t)p1 * I_DIM + kh;
    #pragma unroll
    for (int ks = 0; ks < 4; ++ks) {
      short8 a0 = *(const short8*)(ap0 + ks * 32 + ko);
      short8 a1 = *(const short8*)(ap1 + ks * 32 + ko);
      #pragma unroll
      for (int cf = 0; cf < 6; ++cf) {
        short8 b = *(const short8*)&Ds[ch * 96 + cf * 16 + (l & 15)][ks * 32 + ko];
        acc[0][cf] = mfma16(a0, b, acc[0][cf]);
        acc[1][cf] = mfma16(a1, b, acc[1][cf]);
      }
    }
  }

  const int rgrp = l >> 4, col_l = l & 15;
  #pragma unroll
  for (int tr = 0; tr < 2; ++tr)
    #pragma unroll
    for (int j = 0; j < 4; ++j) {
      int r = tf * 32 + tr * 16 + rgrp * 4 + j;
      if (r < tm) {
        float w = sws[r];
        int trow = tks[r];
        #pragma unroll
        for (int cf = 0; cf < 6; ++cf) {
          int hcol = h0 + ch * 96 + cf * 16 + col_l;
          atomicAdd(&out[(size_t)trow * H_DIM + hcol], acc[tr][cf][j] * w);
        }
      }
    }
}

extern "C" void kernel_launch(void* const* d_in, const int* in_sizes, int n_in,
                              void* d_out, int out_size, void* d_ws, size_t ws_size,
                              hipStream_t stream) {
  const float* x  = (const float*)d_in[0];
  const float* rw = (const float*)d_in[1];
  const float* wg = (const float*)d_in[2];
  const float* wu = (const float*)d_in[3];
  const float* wd = (const float*)d_in[4];
  float* out = (float*)d_out;

  char* ws = (char*)d_ws;
  int*    topi    = (int*)(ws + 0);          // 16384 ints
  float*  topw    = (float*)(ws + 65536);    // 16384 floats
  int*    counts  = (int*)(ws + 131072);
  int*    offsets = (int*)(ws + 131584);
  int*    cursor  = (int*)(ws + 132096);
  int*    toklist = (int*)(ws + 132608);     // 16384 ints
  float*  wlist   = (float*)(ws + 198144);   // 16384 floats
  ushort* xbf     = (ushort*)(ws + 264192);  // 2048*768 bf16 = 3 MB
  ushort* hmid    = (ushort*)(ws + 3409920); // 16384*256 bf16 = 8 MB (end ~11.3 MB)
  // router partials [3][2048][64] fp32 (1.5 MB) overlap the hmid region:
  // consumed by router_topk BEFORE k1 writes hmid. No liveness overlap.
  float*  rpart   = (float*)(ws + 3409920);

  hipMemsetAsync(counts, 0, E_NUM * sizeof(int), stream);
  hipMemsetAsync(d_out, 0, (size_t)out_size * sizeof(float), stream);

  cvt_x_kernel<<<(N_TOK * H_DIM / 8) / 512, 512, 0, stream>>>(x, xbf);
  router_gemm<<<dim3(N_TOK / 64, 3), 256, 0, stream>>>(x, rw, rpart);
  router_topk<<<N_TOK / 4, 256, 0, stream>>>(rpart, topi, topw, counts);
  prefix_kernel<<<1, 64, 0, stream>>>(counts, offsets, cursor);
  scatter_kernel<<<(NPAIR + 255) / 256, 256, 0, stream>>>(topi, topw, cursor, toklist, wlist);
  k1_gateup<<<dim3(8, E_NUM, (N_TOK + K1_TB - 1) / K1_TB), 512, 0, stream>>>(
      xbf, wg, wu, offsets, toklist, hmid);
  k2_down<<<dim3(4, E_NUM, N_TOK / 128), 512, 0, stream>>>(
      hmid, wd, offsets, toklist, wlist, out);
}

// Round 5
// 272.587 us; speedup vs baseline: 4.9921x; 1.0165x over previous
//
#include <hip/hip_runtime.h>
#include <hip/hip_bf16.h>
#include <math.h>

#define N_TOK 2048
#define H_DIM 768
#define E_NUM 64
#define I_DIM 256
#define TOPK 8
#define NPAIR (N_TOK * TOPK)

typedef __attribute__((ext_vector_type(8))) short short8;
typedef __attribute__((ext_vector_type(4))) float f32x4;

__device__ inline ushort f2bf(float f) {
  unsigned u = __builtin_bit_cast(unsigned, f);
  u += 0x7fffu + ((u >> 16) & 1u);
  return (ushort)(u >> 16);
}

__device__ inline unsigned pack2(float a, float b) {
  return (unsigned)f2bf(a) | ((unsigned)f2bf(b) << 16);
}

__device__ inline f32x4 mfma16(short8 a, short8 b, f32x4 c) {
  return __builtin_amdgcn_mfma_f32_16x16x32_bf16(a, b, c, 0, 0, 0);
}

// ---------------- x fp32 -> bf16 ----------------
__global__ __launch_bounds__(512) void cvt_x_kernel(const float* __restrict__ x,
                                                    ushort* __restrict__ xbf) {
  const int i = blockIdx.x * 512 + threadIdx.x;  // 8 floats per thread
  const float* s = x + (size_t)i * 8;
  short8 r;
  #pragma unroll
  for (int j = 0; j < 8; ++j) r[j] = (short)f2bf(s[j]);
  *(short8*)(xbf + (size_t)i * 8) = r;
}

// ---------------- Router GEMM (fp32, split-K): part[ks][t][e] --------------
#define RT_KC 256
__global__ __launch_bounds__(256) void router_gemm(const float* __restrict__ x,
                                                   const float* __restrict__ rw,
                                                   float* __restrict__ part) {
  const int t0 = blockIdx.x * 64, k0 = blockIdx.y * RT_KC;
  __shared__ float xs[64][68];
  __shared__ float ws[64][68];
  const int tid = threadIdx.x;
  const int tx = tid & 15, ty = tid >> 4;
  float acc[4][4] = {};
  for (int kc = 0; kc < RT_KC; kc += 64) {
    __syncthreads();
    {
      const int r = tid >> 2, q = tid & 3;
      const float4* srcx = (const float4*)&x[(size_t)(t0 + r) * H_DIM + k0 + kc];
      const float4* srcw = (const float4*)&rw[(size_t)r * H_DIM + k0 + kc];
      float4* dstx = (float4*)&xs[r][0];
      float4* dstw = (float4*)&ws[r][0];
      #pragma unroll
      for (int j = 0; j < 4; ++j) {
        dstx[q * 4 + j] = srcx[q * 4 + j];
        dstw[q * 4 + j] = srcw[q * 4 + j];
      }
    }
    __syncthreads();
    #pragma unroll
    for (int k4 = 0; k4 < 16; ++k4) {
      float4 a0 = *(float4*)&xs[ty * 4 + 0][k4 * 4];
      float4 a1 = *(float4*)&xs[ty * 4 + 1][k4 * 4];
      float4 a2 = *(float4*)&xs[ty * 4 + 2][k4 * 4];
      float4 a3 = *(float4*)&xs[ty * 4 + 3][k4 * 4];
      float4 b0 = *(float4*)&ws[tx * 4 + 0][k4 * 4];
      float4 b1 = *(float4*)&ws[tx * 4 + 1][k4 * 4];
      float4 b2 = *(float4*)&ws[tx * 4 + 2][k4 * 4];
      float4 b3 = *(float4*)&ws[tx * 4 + 3][k4 * 4];
      #define RFMA(i, j, av, bv) \
        acc[i][j] = fmaf(av.x, bv.x, fmaf(av.y, bv.y, fmaf(av.z, bv.z, fmaf(av.w, bv.w, acc[i][j]))))
      RFMA(0, 0, a0, b0); RFMA(0, 1, a0, b1); RFMA(0, 2, a0, b2); RFMA(0, 3, a0, b3);
      RFMA(1, 0, a1, b0); RFMA(1, 1, a1, b1); RFMA(1, 2, a1, b2); RFMA(1, 3, a1, b3);
      RFMA(2, 0, a2, b0); RFMA(2, 1, a2, b1); RFMA(2, 2, a2, b2); RFMA(2, 3, a2, b3);
      RFMA(3, 0, a3, b0); RFMA(3, 1, a3, b1); RFMA(3, 2, a3, b2); RFMA(3, 3, a3, b3);
      #undef RFMA
    }
  }
  float* pp = part + ((size_t)blockIdx.y * N_TOK + t0) * E_NUM;
  #pragma unroll
  for (int i = 0; i < 4; ++i)
    #pragma unroll
    for (int j = 0; j < 4; ++j)
      pp[(ty * 4 + i) * E_NUM + tx * 4 + j] = acc[i][j];
}

// ---------------- Router top-k: sum partials -> top8 -> renorm -------------
__global__ __launch_bounds__(256) void router_topk(const float* __restrict__ part,
                                                   int* __restrict__ topi,
                                                   float* __restrict__ topw,
                                                   int* __restrict__ counts) {
  const int t = blockIdx.x * 4 + (threadIdx.x >> 6);
  const int l = threadIdx.x & 63;
  float myv = part[(size_t)t * E_NUM + l] +
              part[((size_t)N_TOK + t) * E_NUM + l] +
              part[((size_t)2 * N_TOK + t) * E_NUM + l];
  float topv[TOPK]; int topx[TOPK];
  #pragma unroll
  for (int k = 0; k < TOPK; ++k) {
    float bv = myv; int bi = l;
    #pragma unroll
    for (int off = 32; off > 0; off >>= 1) {
      float ov = __shfl_xor(bv, off, 64);
      int oi = __shfl_xor(bi, off, 64);
      if (ov > bv || (ov == bv && oi < bi)) { bv = ov; bi = oi; }
    }
    topv[k] = bv; topx[k] = bi;
    if (l == bi) myv = -INFINITY;
  }
  if (l == 0) {
    float mx = topv[0], w[TOPK], s = 0.f;
    #pragma unroll
    for (int k = 0; k < TOPK; ++k) { w[k] = __expf(topv[k] - mx); s += w[k]; }
    float inv = 1.f / s;
    #pragma unroll
    for (int k = 0; k < TOPK; ++k) {
      topi[t * TOPK + k] = topx[k];
      topw[t * TOPK + k] = w[k] * inv;
      atomicAdd(&counts[topx[k]], 1);
    }
  }
}

// ---------------- Prefix sum over expert counts ----------------------------
__global__ void prefix_kernel(const int* __restrict__ counts,
                              int* __restrict__ offsets, int* __restrict__ cursor) {
  if (threadIdx.x == 0) {
    int s = 0;
    for (int e = 0; e < E_NUM; ++e) { offsets[e] = s; cursor[e] = s; s += counts[e]; }
    offsets[E_NUM] = s;
  }
}

// ---------------- Scatter (token,k) pairs into per-expert buckets ----------
__global__ void scatter_kernel(const int* __restrict__ topi, const float* __restrict__ topw,
                               int* __restrict__ cursor,
                               int* __restrict__ toklist, float* __restrict__ wlist) {
  int idx = blockIdx.x * 256 + threadIdx.x;
  if (idx >= NPAIR) return;
  int e = topi[idx];
  int pos = atomicAdd(&cursor[e], 1);
  toklist[pos] = idx >> 3;
  wlist[pos] = topw[idx];
}

// ---------------- K1: gate/up MFMA + SwiGLU -> hmid ------------------------
// block = (i-block of 32 cols, expert, token-block of 384)
// Staging: coalesced float4 row-reads of wg/wu, bf16-convert, transpose on
// LDS write (packed k-pairs, ds_write_b32) into round-2's verified col-major
// Bs[col][k] layout. Fragment reads identical to the round-2 passing kernel.
#define K1_TB 384
#define KC1 192
#define BS_S 200   // col stride (elements); 400B = 16B-aligned col bases
__global__ __launch_bounds__(512) void k1_gateup(const ushort* __restrict__ xbf,
                                                 const float* __restrict__ wg,
                                                 const float* __restrict__ wu,
                                                 const int* __restrict__ offsets,
                                                 const int* __restrict__ toklist,
                                                 ushort* __restrict__ hmid) {
  const int e = blockIdx.y, ib = blockIdx.x;
  const int i0 = ib * 32;
  const int start = offsets[e], cnt = offsets[e + 1] - start;
  const int tokbase = blockIdx.z * K1_TB;
  if (tokbase >= cnt) return;
  const int cntb = min(K1_TB, cnt - tokbase);
  const int ntiles = (cntb + 127) >> 7;

  __shared__ ushort Bs[64][BS_S];     // cols 0-31 gate, 32-63 up
  __shared__ float gbuf[4][32 * 32];
  __shared__ ushort hbuf[128 * 32];
  __shared__ int tks[K1_TB];

  const int tid = threadIdx.x;
  for (int r = tid; r < K1_TB; r += 512)
    tks[r] = toklist[start + tokbase + min(r, cntb - 1)];

  const int l = tid & 63, wid = tid >> 6;
  const int tf = wid & 3, gu = wid >> 6 ? 0 : 0;  // placeholder (recomputed below)
  const int guw = wid >> 2;  // 0 = gate waves, 1 = up waves

  // staging role: quad sq (0-7 gate cols, 8-15 up cols), row-pair index sm
  const int sq = tid & 15, sm = tid >> 4;  // sm 0..31
  const int scol = (sq >> 3) * 32 + (sq & 7) * 4;  // Bs col base of this quad
  const float* sbase = (sq < 8 ? wg : wu) + (size_t)e * H_DIM * I_DIM + i0 + (sq & 7) * 4;

  f32x4 acc[3][2][2] = {};
  const int ko = (l >> 4) * 8;

  for (int kh = 0; kh < H_DIM; kh += KC1) {
    __syncthreads();
    // stage: rows k0=2*(sm+it*32), k0+1; transpose into Bs[col][k] packed pairs
    #pragma unroll
    for (int it = 0; it < 3; ++it) {
      const int k0 = 2 * (sm + it * 32);
      float4 v0 = *(const float4*)(sbase + (size_t)(kh + k0) * I_DIM);
      float4 v1 = *(const float4*)(sbase + (size_t)(kh + k0 + 1) * I_DIM);
      *(unsigned*)&Bs[scol + 0][k0] = pack2(v0.x, v1.x);
      *(unsigned*)&Bs[scol + 1][k0] = pack2(v0.y, v1.y);
      *(unsigned*)&Bs[scol + 2][k0] = pack2(v0.z, v1.z);
      *(unsigned*)&Bs[scol + 3][k0] = pack2(v0.w, v1.w);
    }
    __syncthreads();
    #pragma unroll
    for (int ks = 0; ks < KC1 / 32; ++ks) {
      short8 b0 = *(const short8*)&Bs[guw * 32 + (l & 15)][ks * 32 + ko];
      short8 b1 = *(const short8*)&Bs[guw * 32 + 16 + (l & 15)][ks * 32 + ko];
      #pragma unroll
      for (int tile = 0; tile < 3; ++tile) {
        if (tile < ntiles) {
          const size_t off = (size_t)kh + ks * 32 + ko;
          short8 a0 = *(const short8*)(xbf + (size_t)tks[tile * 128 + tf * 32 + (l & 15)] * H_DIM + off);
          short8 a1 = *(const short8*)(xbf + (size_t)tks[tile * 128 + tf * 32 + 16 + (l & 15)] * H_DIM + off);
          acc[tile][0][0] = mfma16(a0, b0, acc[tile][0][0]);
          acc[tile][1][0] = mfma16(a1, b0, acc[tile][1][0]);
          acc[tile][0][1] = mfma16(a0, b1, acc[tile][0][1]);
          acc[tile][1][1] = mfma16(a1, b1, acc[tile][1][1]);
        }
      }
    }
  }

  // epilogue: SwiGLU exchange gate<->up waves, then store hmid
  const int rgrp = l >> 4, col_l = l & 15;
  #pragma unroll
  for (int tile = 0; tile < 3; ++tile) {
    if (tile >= ntiles) break;
    const int tm = min(128, cntb - tile * 128);
    __syncthreads();
    if (guw == 0) {
      #pragma unroll
      for (int tr = 0; tr < 2; ++tr)
        #pragma unroll
        for (int cf = 0; cf < 2; ++cf)
          #pragma unroll
          for (int j = 0; j < 4; ++j) {
            int row = tr * 16 + rgrp * 4 + j, col = cf * 16 + col_l;
            gbuf[tf][row * 32 + col] = acc[tile][tr][cf][j];
          }
    }
    __syncthreads();
    if (guw == 1) {
      #pragma unroll
      for (int tr = 0; tr < 2; ++tr)
        #pragma unroll
        for (int cf = 0; cf < 2; ++cf)
          #pragma unroll
          for (int j = 0; j < 4; ++j) {
            int row = tr * 16 + rgrp * 4 + j, col = cf * 16 + col_l;
            float g = gbuf[tf][row * 32 + col];
            float hm = g / (1.f + __expf(-g)) * acc[tile][tr][cf][j];
            hbuf[(tf * 32 + row) * 32 + col] = f2bf(hm);
          }
    }
    __syncthreads();
    {
      const int row = tid >> 2, part = tid & 3;
      if (row < tm) {
        ushort* dst = hmid + (size_t)(start + tokbase + tile * 128 + row) * I_DIM + i0 + part * 8;
        *(short8*)dst = *(const short8*)&hbuf[row * 32 + part * 8];
      }
    }
  }
}

// ---------------- K2: down-proj MFMA, weighted atomic accumulate -----------
// block = (h-slice of 192, expert, token-block of 128); same staging scheme.
#define KC2 128
#define DS_S 136
__global__ __launch_bounds__(512) void k2_down(const ushort* __restrict__ hmid,
                                               const float* __restrict__ wd,
                                               const int* __restrict__ offsets,
                                               const int* __restrict__ toklist,
                                               const float* __restrict__ wlist,
                                               float* __restrict__ out) {
  const int e = blockIdx.y, hs = blockIdx.x;
  const int h0 = hs * 192;
  const int start = offsets[e], cnt = offsets[e + 1] - start;
  const int tokbase = blockIdx.z * 128;
  if (tokbase >= cnt) return;
  const int tm = min(128, cnt - tokbase);

  __shared__ ushort Ds[192][DS_S];  // col-major [h-col][k]
  __shared__ float sws[128];
  __shared__ int tks[128];

  const int tid = threadIdx.x;
  if (tid < 128) {
    int p = start + tokbase + min(tid, tm - 1);
    sws[tid] = (tid < tm) ? wlist[p] : 0.f;
    tks[tid] = toklist[p];
  }

  const int l = tid & 63, wid = tid >> 6;
  const int tf = wid & 3, ch = wid >> 2;
  f32x4 acc[2][6] = {};

  const int p0 = min(start + tokbase + tf * 32 + (l & 15), NPAIR - 1);
  const int p1 = min(start + tokbase + tf * 32 + 16 + (l & 15), NPAIR - 1);
  const int ko = (l >> 4) * 8;

  const float* wde = wd + (size_t)e * I_DIM * H_DIM;

  for (int kh = 0; kh < I_DIM; kh += KC2) {
    __syncthreads();
    // stage: 64 row-pairs x 48 quads; transpose into Ds[col][k] packed pairs
    #pragma unroll
    for (int it = 0; it < 6; ++it) {
      int idx = tid + it * 512;
      int q = idx % 48, m = idx / 48;  // m 0..63
      const int k0 = 2 * m;
      const float* src = wde + (size_t)(kh + k0) * H_DIM + h0 + q * 4;
      float4 v0 = *(const float4*)src;
      float4 v1 = *(const float4*)(src + H_DIM);
      *(unsigned*)&Ds[q * 4 + 0][k0] = pack2(v0.x, v1.x);
      *(unsigned*)&Ds[q * 4 + 1][k0] = pack2(v0.y, v1.y);
      *(unsigned*)&Ds[q * 4 + 2][k0] = pack2(v0.z, v1.z);
      *(unsigned*)&Ds[q * 4 + 3][k0] = pack2(v0.w, v1.w);
    }
    __syncthreads();
    const ushort* ap0 = hmid + (size_t)p0 * I_DIM + kh;
    const ushort* ap1 = hmid + (size_t)p1 * I_DIM + kh;
    #pragma unroll
    for (int ks = 0; ks < KC2 / 32; ++ks) {
      short8 a0 = *(const short8*)(ap0 + ks * 32 + ko);
      short8 a1 = *(const short8*)(ap1 + ks * 32 + ko);
      #pragma unroll
      for (int cf = 0; cf < 6; ++cf) {
        short8 b = *(const short8*)&Ds[ch * 96 + cf * 16 + (l & 15)][ks * 32 + ko];
        acc[0][cf] = mfma16(a0, b, acc[0][cf]);
        acc[1][cf] = mfma16(a1, b, acc[1][cf]);
      }
    }
  }

  const int rgrp = l >> 4, col_l = l & 15;
  #pragma unroll
  for (int tr = 0; tr < 2; ++tr)
    #pragma unroll
    for (int j = 0; j < 4; ++j) {
      int r = tf * 32 + tr * 16 + rgrp * 4 + j;
      if (r < tm) {
        float w = sws[r];
        int trow = tks[r];
        #pragma unroll
        for (int cf = 0; cf < 6; ++cf) {
          int hcol = h0 + ch * 96 + cf * 16 + col_l;
          atomicAdd(&out[(size_t)trow * H_DIM + hcol], acc[tr][cf][j] * w);
        }
      }
    }
}

extern "C" void kernel_launch(void* const* d_in, const int* in_sizes, int n_in,
                              void* d_out, int out_size, void* d_ws, size_t ws_size,
                              hipStream_t stream) {
  const float* x  = (const float*)d_in[0];
  const float* rw = (const float*)d_in[1];
  const float* wg = (const float*)d_in[2];
  const float* wu = (const float*)d_in[3];
  const float* wd = (const float*)d_in[4];
  float* out = (float*)d_out;

  char* ws = (char*)d_ws;
  int*    topi    = (int*)(ws + 0);
  float*  topw    = (float*)(ws + 65536);
  int*    counts  = (int*)(ws + 131072);
  int*    offsets = (int*)(ws + 131584);
  int*    cursor  = (int*)(ws + 132096);
  int*    toklist = (int*)(ws + 132608);
  float*  wlist   = (float*)(ws + 198144);
  ushort* xbf     = (ushort*)(ws + 264192);   // 3 MB
  ushort* hmid    = (ushort*)(ws + 3409920);  // 8 MB
  float*  rpart   = (float*)(ws + 3409920);   // overlaps hmid; dead before k1

  hipMemsetAsync(counts, 0, E_NUM * sizeof(int), stream);
  hipMemsetAsync(d_out, 0, (size_t)out_size * sizeof(float), stream);

  cvt_x_kernel<<<(N_TOK * H_DIM / 8) / 512, 512, 0, stream>>>(x, xbf);
  router_gemm<<<dim3(N_TOK / 64, 3), 256, 0, stream>>>(x, rw, rpart);
  router_topk<<<N_TOK / 4, 256, 0, stream>>>(rpart, topi, topw, counts);
  prefix_kernel<<<1, 64, 0, stream>>>(counts, offsets, cursor);
  scatter_kernel<<<(NPAIR + 255) / 256, 256, 0, stream>>>(topi, topw, cursor, toklist, wlist);
  k1_gateup<<<dim3(8, E_NUM, (N_TOK + K1_TB - 1) / K1_TB), 512, 0, stream>>>(
      xbf, wg, wu, offsets, toklist, hmid);
  k2_down<<<dim3(4, E_NUM, N_TOK / 128), 512, 0, stream>>>(
      hmid, wd, offsets, toklist, wlist, out);
}

// Round 6
// 208.562 us; speedup vs baseline: 6.5246x; 1.3070x over previous
//
#include <hip/hip_runtime.h>
#include <hip/hip_bf16.h>
#include <math.h>

#define N_TOK 2048
#define H_DIM 768
#define E_NUM 64
#define I_DIM 256
#define TOPK 8
#define NPAIR (N_TOK * TOPK)

typedef __attribute__((ext_vector_type(8))) short short8;
typedef __attribute__((ext_vector_type(4))) float f32x4;

__device__ inline ushort f2bf(float f) {
  unsigned u = __builtin_bit_cast(unsigned, f);
  u += 0x7fffu + ((u >> 16) & 1u);
  return (ushort)(u >> 16);
}

__device__ inline unsigned pack2(float a, float b) {
  return (unsigned)f2bf(a) | ((unsigned)f2bf(b) << 16);
}

__device__ inline f32x4 mfma16(short8 a, short8 b, f32x4 c) {
  return __builtin_amdgcn_mfma_f32_16x16x32_bf16(a, b, c, 0, 0, 0);
}

// ---------------- x fp32 -> bf16 ----------------
__global__ __launch_bounds__(512) void cvt_x_kernel(const float* __restrict__ x,
                                                    ushort* __restrict__ xbf) {
  const int i = blockIdx.x * 512 + threadIdx.x;  // 8 floats per thread
  const float* s = x + (size_t)i * 8;
  short8 r;
  #pragma unroll
  for (int j = 0; j < 8; ++j) r[j] = (short)f2bf(s[j]);
  *(short8*)(xbf + (size_t)i * 8) = r;
}

// ---------------- Router GEMM (fp32, split-K): part[ks][t][e] --------------
#define RT_KC 256
__global__ __launch_bounds__(256) void router_gemm(const float* __restrict__ x,
                                                   const float* __restrict__ rw,
                                                   float* __restrict__ part) {
  const int t0 = blockIdx.x * 64, k0 = blockIdx.y * RT_KC;
  __shared__ float xs[64][68];
  __shared__ float ws[64][68];
  const int tid = threadIdx.x;
  const int tx = tid & 15, ty = tid >> 4;
  float acc[4][4] = {};
  for (int kc = 0; kc < RT_KC; kc += 64) {
    __syncthreads();
    {
      const int r = tid >> 2, q = tid & 3;
      const float4* srcx = (const float4*)&x[(size_t)(t0 + r) * H_DIM + k0 + kc];
      const float4* srcw = (const float4*)&rw[(size_t)r * H_DIM + k0 + kc];
      float4* dstx = (float4*)&xs[r][0];
      float4* dstw = (float4*)&ws[r][0];
      #pragma unroll
      for (int j = 0; j < 4; ++j) {
        dstx[q * 4 + j] = srcx[q * 4 + j];
        dstw[q * 4 + j] = srcw[q * 4 + j];
      }
    }
    __syncthreads();
    #pragma unroll
    for (int k4 = 0; k4 < 16; ++k4) {
      float4 a0 = *(float4*)&xs[ty * 4 + 0][k4 * 4];
      float4 a1 = *(float4*)&xs[ty * 4 + 1][k4 * 4];
      float4 a2 = *(float4*)&xs[ty * 4 + 2][k4 * 4];
      float4 a3 = *(float4*)&xs[ty * 4 + 3][k4 * 4];
      float4 b0 = *(float4*)&ws[tx * 4 + 0][k4 * 4];
      float4 b1 = *(float4*)&ws[tx * 4 + 1][k4 * 4];
      float4 b2 = *(float4*)&ws[tx * 4 + 2][k4 * 4];
      float4 b3 = *(float4*)&ws[tx * 4 + 3][k4 * 4];
      #define RFMA(i, j, av, bv) \
        acc[i][j] = fmaf(av.x, bv.x, fmaf(av.y, bv.y, fmaf(av.z, bv.z, fmaf(av.w, bv.w, acc[i][j]))))
      RFMA(0, 0, a0, b0); RFMA(0, 1, a0, b1); RFMA(0, 2, a0, b2); RFMA(0, 3, a0, b3);
      RFMA(1, 0, a1, b0); RFMA(1, 1, a1, b1); RFMA(1, 2, a1, b2); RFMA(1, 3, a1, b3);
      RFMA(2, 0, a2, b0); RFMA(2, 1, a2, b1); RFMA(2, 2, a2, b2); RFMA(2, 3, a2, b3);
      RFMA(3, 0, a3, b0); RFMA(3, 1, a3, b1); RFMA(3, 2, a3, b2); RFMA(3, 3, a3, b3);
      #undef RFMA
    }
  }
  float* pp = part + ((size_t)blockIdx.y * N_TOK + t0) * E_NUM;
  #pragma unroll
  for (int i = 0; i < 4; ++i)
    #pragma unroll
    for (int j = 0; j < 4; ++j)
      pp[(ty * 4 + i) * E_NUM + tx * 4 + j] = acc[i][j];
}

// ---------------- Router top-k: sum partials -> top8 -> renorm -------------
// NO global atomics (histogram moved to hist_prefix_kernel).
__global__ __launch_bounds__(256) void router_topk(const float* __restrict__ part,
                                                   int* __restrict__ topi,
                                                   float* __restrict__ topw) {
  const int t = blockIdx.x * 4 + (threadIdx.x >> 6);
  const int l = threadIdx.x & 63;
  float myv = part[(size_t)t * E_NUM + l] +
              part[((size_t)N_TOK + t) * E_NUM + l] +
              part[((size_t)2 * N_TOK + t) * E_NUM + l];
  float topv[TOPK]; int topx[TOPK];
  #pragma unroll
  for (int k = 0; k < TOPK; ++k) {
    float bv = myv; int bi = l;
    #pragma unroll
    for (int off = 32; off > 0; off >>= 1) {
      float ov = __shfl_xor(bv, off, 64);
      int oi = __shfl_xor(bi, off, 64);
      if (ov > bv || (ov == bv && oi < bi)) { bv = ov; bi = oi; }
    }
    topv[k] = bv; topx[k] = bi;
    if (l == bi) myv = -INFINITY;
  }
  if (l == 0) {
    float mx = topv[0], w[TOPK], s = 0.f;
    #pragma unroll
    for (int k = 0; k < TOPK; ++k) { w[k] = __expf(topv[k] - mx); s += w[k]; }
    float inv = 1.f / s;
    #pragma unroll
    for (int k = 0; k < TOPK; ++k) {
      topi[t * TOPK + k] = topx[k];
      topw[t * TOPK + k] = w[k] * inv;
    }
  }
}

// ---------------- Histogram (LDS atomics) + prefix, single block -----------
__global__ __launch_bounds__(256) void hist_prefix_kernel(const int* __restrict__ topi,
                                                          int* __restrict__ offsets) {
  __shared__ int h[E_NUM];
  const int tid = threadIdx.x;
  if (tid < E_NUM) h[tid] = 0;
  __syncthreads();
  for (int i = tid; i < NPAIR; i += 256) atomicAdd(&h[topi[i]], 1);
  __syncthreads();
  if (tid == 0) {
    int s = 0;
    for (int e = 0; e < E_NUM; ++e) { offsets[e] = s; s += h[e]; }
    offsets[E_NUM] = s;
  }
}

// ---------------- Scatter: one block per expert, ordered ballot compaction -
// Deterministic (token-ascending within expert), zero global atomics.
__global__ __launch_bounds__(256) void scatter64(const int* __restrict__ topi,
                                                 const float* __restrict__ topw,
                                                 const int* __restrict__ offsets,
                                                 int* __restrict__ toklist,
                                                 float* __restrict__ wlist) {
  const int e = blockIdx.x;
  const int tid = threadIdx.x, l = tid & 63, w = tid >> 6;
  __shared__ int wcnt[4];
  __shared__ int base;
  if (tid == 0) base = offsets[e];
  __syncthreads();
  for (int c = 0; c < NPAIR; c += 256) {
    const int idx = c + tid;
    const bool p = (topi[idx] == e);
    const unsigned long long m = __ballot(p);
    if (l == 0) wcnt[w] = __popcll(m);
    __syncthreads();
    int off = base;
    for (int ww = 0; ww < 4; ++ww)
      if (ww < w) off += wcnt[ww];
    if (p) {
      const int pos = off + __popcll(m & ((1ull << l) - 1ull));
      toklist[pos] = idx >> 3;
      wlist[pos] = topw[idx];
    }
    __syncthreads();
    if (tid == 0) base += wcnt[0] + wcnt[1] + wcnt[2] + wcnt[3];
    __syncthreads();
  }
}

// ---------------- K1: gate/up MFMA + SwiGLU -> hmid ------------------------
// block = (i-block of 32 cols, expert, token-block of 256)
// x-tile staged in LDS per 64-wide K-chunk (coalesced 128B row segments);
// A and B fragments both from LDS. Epilogue buffers overlay the x-tile.
#define K1_TB 256
#define KC1 64
#define XS_S 72   // row stride in ushorts; 144 B = 16B-aligned, 2-way banks
__global__ __launch_bounds__(512) void k1_gateup(const ushort* __restrict__ xbf,
                                                 const float* __restrict__ wg,
                                                 const float* __restrict__ wu,
                                                 const int* __restrict__ offsets,
                                                 const int* __restrict__ toklist,
                                                 ushort* __restrict__ hmid) {
  const int e = blockIdx.y, ib = blockIdx.x;
  const int i0 = ib * 32;
  const int start = offsets[e], cnt = offsets[e + 1] - start;
  const int tokbase = blockIdx.z * K1_TB;
  if (tokbase >= cnt) return;
  const int cntb = min(K1_TB, cnt - tokbase);
  const int ntiles = (cntb + 127) >> 7;

  __shared__ __align__(16) char smem[47104];
  ushort* xs = (ushort*)smem;                 // [256][XS_S]  36864 B
  ushort* Bs = (ushort*)(smem + 36864);       // [64][XS_S]   9216 B (cols 0-31 gate, 32-63 up)
  int*    tks = (int*)(smem + 46080);         // [256]        1024 B
  float*  gbuf = (float*)smem;                // epilogue overlay [4][1024]
  ushort* hbuf = (ushort*)(smem + 16384);     // epilogue overlay [128*32]

  const int tid = threadIdx.x;
  if (tid < K1_TB)
    tks[tid] = toklist[start + tokbase + min(tid, cntb - 1)];

  const int l = tid & 63, wid = tid >> 6;
  const int tf = wid & 3, guw = wid >> 2;  // 0 = gate waves, 1 = up waves

  // B staging role: quad sq (0-7 gate cols, 8-15 up cols), row-pair sm
  const int sq = tid & 15, sm = tid >> 4;           // sm 0..31
  const int scol = (sq >> 3) * 32 + (sq & 7) * 4;   // Bs col base
  const float* sbase = (sq < 8 ? wg : wu) + (size_t)e * H_DIM * I_DIM + i0 + (sq & 7) * 4;

  f32x4 acc[2][2][2] = {};
  const int ko = (l >> 4) * 8;

  for (int kh = 0; kh < H_DIM; kh += KC1) {
    __syncthreads();
    // stage x-tile chunk: 256 rows x 64 cols, 8 consecutive lanes per row
    #pragma unroll
    for (int it = 0; it < 4; ++it) {
      const int u = tid + it * 512;
      const int row = u >> 3, col8 = u & 7;
      *(short8*)&xs[row * XS_S + col8 * 8] =
          *(const short8*)(xbf + (size_t)tks[row] * H_DIM + kh + col8 * 8);
    }
    // stage B chunk: 64 k-rows x 64 cols, transpose via packed k-pairs
    {
      const int k0 = 2 * sm;
      float4 v0 = *(const float4*)(sbase + (size_t)(kh + k0) * I_DIM);
      float4 v1 = *(const float4*)(sbase + (size_t)(kh + k0 + 1) * I_DIM);
      *(unsigned*)&Bs[(scol + 0) * XS_S + k0] = pack2(v0.x, v1.x);
      *(unsigned*)&Bs[(scol + 1) * XS_S + k0] = pack2(v0.y, v1.y);
      *(unsigned*)&Bs[(scol + 2) * XS_S + k0] = pack2(v0.z, v1.z);
      *(unsigned*)&Bs[(scol + 3) * XS_S + k0] = pack2(v0.w, v1.w);
    }
    __syncthreads();
    #pragma unroll
    for (int ks = 0; ks < KC1 / 32; ++ks) {
      const int kofs = ks * 32 + ko;
      short8 b0 = *(const short8*)&Bs[(guw * 32 + (l & 15)) * XS_S + kofs];
      short8 b1 = *(const short8*)&Bs[(guw * 32 + 16 + (l & 15)) * XS_S + kofs];
      #pragma unroll
      for (int tile = 0; tile < 2; ++tile) {
        if (tile < ntiles) {
          short8 a0 = *(const short8*)&xs[(tile * 128 + tf * 32 + (l & 15)) * XS_S + kofs];
          short8 a1 = *(const short8*)&xs[(tile * 128 + tf * 32 + 16 + (l & 15)) * XS_S + kofs];
          acc[tile][0][0] = mfma16(a0, b0, acc[tile][0][0]);
          acc[tile][1][0] = mfma16(a1, b0, acc[tile][1][0]);
          acc[tile][0][1] = mfma16(a0, b1, acc[tile][0][1]);
          acc[tile][1][1] = mfma16(a1, b1, acc[tile][1][1]);
        }
      }
    }
  }

  // epilogue: SwiGLU exchange gate<->up waves, then store hmid
  const int rgrp = l >> 4, col_l = l & 15;
  #pragma unroll
  for (int tile = 0; tile < 2; ++tile) {
    if (tile >= ntiles) break;
    const int tm = min(128, cntb - tile * 128);
    __syncthreads();
    if (guw == 0) {
      #pragma unroll
      for (int tr = 0; tr < 2; ++tr)
        #pragma unroll
        for (int cf = 0; cf < 2; ++cf)
          #pragma unroll
          for (int j = 0; j < 4; ++j) {
            int row = tr * 16 + rgrp * 4 + j, col = cf * 16 + col_l;
            gbuf[tf * 1024 + row * 32 + col] = acc[tile][tr][cf][j];
          }
    }
    __syncthreads();
    if (guw == 1) {
      #pragma unroll
      for (int tr = 0; tr < 2; ++tr)
        #pragma unroll
        for (int cf = 0; cf < 2; ++cf)
          #pragma unroll
          for (int j = 0; j < 4; ++j) {
            int row = tr * 16 + rgrp * 4 + j, col = cf * 16 + col_l;
            float g = gbuf[tf * 1024 + row * 32 + col];
            float hm = g / (1.f + __expf(-g)) * acc[tile][tr][cf][j];
            hbuf[(tf * 32 + row) * 32 + col] = f2bf(hm);
          }
    }
    __syncthreads();
    {
      const int row = tid >> 2, part = tid & 3;
      if (row < tm) {
        ushort* dst = hmid + (size_t)(start + tokbase + tile * 128 + row) * I_DIM + i0 + part * 8;
        *(short8*)dst = *(const short8*)&hbuf[row * 32 + part * 8];
      }
    }
  }
}

// ---------------- K2: down-proj MFMA, weighted atomic accumulate -----------
// block = (h-slice of 192, expert, token-block of 128); unchanged from R5.
#define KC2 128
#define DS_S 136
__global__ __launch_bounds__(512) void k2_down(const ushort* __restrict__ hmid,
                                               const float* __restrict__ wd,
                                               const int* __restrict__ offsets,
                                               const int* __restrict__ toklist,
                                               const float* __restrict__ wlist,
                                               float* __restrict__ out) {
  const int e = blockIdx.y, hs = blockIdx.x;
  const int h0 = hs * 192;
  const int start = offsets[e], cnt = offsets[e + 1] - start;
  const int tokbase = blockIdx.z * 128;
  if (tokbase >= cnt) return;
  const int tm = min(128, cnt - tokbase);

  __shared__ ushort Ds[192][DS_S];
  __shared__ float sws[128];
  __shared__ int tks[128];

  const int tid = threadIdx.x;
  if (tid < 128) {
    int p = start + tokbase + min(tid, tm - 1);
    sws[tid] = (tid < tm) ? wlist[p] : 0.f;
    tks[tid] = toklist[p];
  }

  const int l = tid & 63, wid = tid >> 6;
  const int tf = wid & 3, ch = wid >> 2;
  f32x4 acc[2][6] = {};

  const int p0 = min(start + tokbase + tf * 32 + (l & 15), NPAIR - 1);
  const int p1 = min(start + tokbase + tf * 32 + 16 + (l & 15), NPAIR - 1);
  const int ko = (l >> 4) * 8;

  const float* wde = wd + (size_t)e * I_DIM * H_DIM;

  for (int kh = 0; kh < I_DIM; kh += KC2) {
    __syncthreads();
    #pragma unroll
    for (int it = 0; it < 6; ++it) {
      int idx = tid + it * 512;
      int q = idx % 48, m = idx / 48;
      const int k0 = 2 * m;
      const float* src = wde + (size_t)(kh + k0) * H_DIM + h0 + q * 4;
      float4 v0 = *(const float4*)src;
      float4 v1 = *(const float4*)(src + H_DIM);
      *(unsigned*)&Ds[q * 4 + 0][k0] = pack2(v0.x, v1.x);
      *(unsigned*)&Ds[q * 4 + 1][k0] = pack2(v0.y, v1.y);
      *(unsigned*)&Ds[q * 4 + 2][k0] = pack2(v0.z, v1.z);
      *(unsigned*)&Ds[q * 4 + 3][k0] = pack2(v0.w, v1.w);
    }
    __syncthreads();
    const ushort* ap0 = hmid + (size_t)p0 * I_DIM + kh;
    const ushort* ap1 = hmid + (size_t)p1 * I_DIM + kh;
    #pragma unroll
    for (int ks = 0; ks < KC2 / 32; ++ks) {
      short8 a0 = *(const short8*)(ap0 + ks * 32 + ko);
      short8 a1 = *(const short8*)(ap1 + ks * 32 + ko);
      #pragma unroll
      for (int cf = 0; cf < 6; ++cf) {
        short8 b = *(const short8*)&Ds[ch * 96 + cf * 16 + (l & 15)][ks * 32 + ko];
        acc[0][cf] = mfma16(a0, b, acc[0][cf]);
        acc[1][cf] = mfma16(a1, b, acc[1][cf]);
      }
    }
  }

  const int rgrp = l >> 4, col_l = l & 15;
  #pragma unroll
  for (int tr = 0; tr < 2; ++tr)
    #pragma unroll
    for (int j = 0; j < 4; ++j) {
      int r = tf * 32 + tr * 16 + rgrp * 4 + j;
      if (r < tm) {
        float w = sws[r];
        int trow = tks[r];
        #pragma unroll
        for (int cf = 0; cf < 6; ++cf) {
          int hcol = h0 + ch * 96 + cf * 16 + col_l;
          atomicAdd(&out[(size_t)trow * H_DIM + hcol], acc[tr][cf][j] * w);
        }
      }
    }
}

extern "C" void kernel_launch(void* const* d_in, const int* in_sizes, int n_in,
                              void* d_out, int out_size, void* d_ws, size_t ws_size,
                              hipStream_t stream) {
  const float* x  = (const float*)d_in[0];
  const float* rw = (const float*)d_in[1];
  const float* wg = (const float*)d_in[2];
  const float* wu = (const float*)d_in[3];
  const float* wd = (const float*)d_in[4];
  float* out = (float*)d_out;

  char* ws = (char*)d_ws;
  int*    topi    = (int*)(ws + 0);
  float*  topw    = (float*)(ws + 65536);
  int*    offsets = (int*)(ws + 131584);
  int*    toklist = (int*)(ws + 132608);
  float*  wlist   = (float*)(ws + 198144);
  ushort* xbf     = (ushort*)(ws + 264192);   // 3 MB
  ushort* hmid    = (ushort*)(ws + 3409920);  // 8 MB
  float*  rpart   = (float*)(ws + 3409920);   // overlaps hmid; dead before k1

  hipMemsetAsync(d_out, 0, (size_t)out_size * sizeof(float), stream);

  cvt_x_kernel<<<(N_TOK * H_DIM / 8) / 512, 512, 0, stream>>>(x, xbf);
  router_gemm<<<dim3(N_TOK / 64, 3), 256, 0, stream>>>(x, rw, rpart);
  router_topk<<<N_TOK / 4, 256, 0, stream>>>(rpart, topi, topw);
  hist_prefix_kernel<<<1, 256, 0, stream>>>(topi, offsets);
  scatter64<<<E_NUM, 256, 0, stream>>>(topi, topw, offsets, toklist, wlist);
  k1_gateup<<<dim3(8, E_NUM, N_TOK / K1_TB), 512, 0, stream>>>(
      xbf, wg, wu, offsets, toklist, hmid);
  k2_down<<<dim3(4, E_NUM, N_TOK / 128), 512, 0, stream>>>(
      hmid, wd, offsets, toklist, wlist, out);
}

// Round 7
// 178.300 us; speedup vs baseline: 7.6320x; 1.1697x over previous
//
#include <hip/hip_runtime.h>
#include <hip/hip_bf16.h>
#include <math.h>

#define N_TOK 2048
#define H_DIM 768
#define E_NUM 64
#define I_DIM 256
#define TOPK 8
#define NPAIR (N_TOK * TOPK)

typedef __attribute__((ext_vector_type(8))) short short8;
typedef __attribute__((ext_vector_type(4))) float f32x4;

__device__ inline ushort f2bf(float f) {
  unsigned u = __builtin_bit_cast(unsigned, f);
  u += 0x7fffu + ((u >> 16) & 1u);
  return (ushort)(u >> 16);
}

__device__ inline unsigned pack2(float a, float b) {
  return (unsigned)f2bf(a) | ((unsigned)f2bf(b) << 16);
}

__device__ inline f32x4 mfma16(short8 a, short8 b, f32x4 c) {
  return __builtin_amdgcn_mfma_f32_16x16x32_bf16(a, b, c, 0, 0, 0);
}

// ---------------- x fp32 -> bf16 ----------------
__global__ __launch_bounds__(512) void cvt_x_kernel(const float* __restrict__ x,
                                                    ushort* __restrict__ xbf) {
  const int i = blockIdx.x * 512 + threadIdx.x;
  const float* s = x + (size_t)i * 8;
  short8 r;
  #pragma unroll
  for (int j = 0; j < 8; ++j) r[j] = (short)f2bf(s[j]);
  *(short8*)(xbf + (size_t)i * 8) = r;
}

// ---------------- Router GEMM (fp32, split-K): part[ks][t][e] --------------
#define RT_KC 256
__global__ __launch_bounds__(256) void router_gemm(const float* __restrict__ x,
                                                   const float* __restrict__ rw,
                                                   float* __restrict__ part) {
  const int t0 = blockIdx.x * 64, k0 = blockIdx.y * RT_KC;
  __shared__ float xs[64][68];
  __shared__ float ws[64][68];
  const int tid = threadIdx.x;
  const int tx = tid & 15, ty = tid >> 4;
  float acc[4][4] = {};
  for (int kc = 0; kc < RT_KC; kc += 64) {
    __syncthreads();
    {
      const int r = tid >> 2, q = tid & 3;
      const float4* srcx = (const float4*)&x[(size_t)(t0 + r) * H_DIM + k0 + kc];
      const float4* srcw = (const float4*)&rw[(size_t)r * H_DIM + k0 + kc];
      float4* dstx = (float4*)&xs[r][0];
      float4* dstw = (float4*)&ws[r][0];
      #pragma unroll
      for (int j = 0; j < 4; ++j) {
        dstx[q * 4 + j] = srcx[q * 4 + j];
        dstw[q * 4 + j] = srcw[q * 4 + j];
      }
    }
    __syncthreads();
    #pragma unroll
    for (int k4 = 0; k4 < 16; ++k4) {
      float4 a0 = *(float4*)&xs[ty * 4 + 0][k4 * 4];
      float4 a1 = *(float4*)&xs[ty * 4 + 1][k4 * 4];
      float4 a2 = *(float4*)&xs[ty * 4 + 2][k4 * 4];
      float4 a3 = *(float4*)&xs[ty * 4 + 3][k4 * 4];
      float4 b0 = *(float4*)&ws[tx * 4 + 0][k4 * 4];
      float4 b1 = *(float4*)&ws[tx * 4 + 1][k4 * 4];
      float4 b2 = *(float4*)&ws[tx * 4 + 2][k4 * 4];
      float4 b3 = *(float4*)&ws[tx * 4 + 3][k4 * 4];
      #define RFMA(i, j, av, bv) \
        acc[i][j] = fmaf(av.x, bv.x, fmaf(av.y, bv.y, fmaf(av.z, bv.z, fmaf(av.w, bv.w, acc[i][j]))))
      RFMA(0, 0, a0, b0); RFMA(0, 1, a0, b1); RFMA(0, 2, a0, b2); RFMA(0, 3, a0, b3);
      RFMA(1, 0, a1, b0); RFMA(1, 1, a1, b1); RFMA(1, 2, a1, b2); RFMA(1, 3, a1, b3);
      RFMA(2, 0, a2, b0); RFMA(2, 1, a2, b1); RFMA(2, 2, a2, b2); RFMA(2, 3, a2, b3);
      RFMA(3, 0, a3, b0); RFMA(3, 1, a3, b1); RFMA(3, 2, a3, b2); RFMA(3, 3, a3, b3);
      #undef RFMA
    }
  }
  float* pp = part + ((size_t)blockIdx.y * N_TOK + t0) * E_NUM;
  #pragma unroll
  for (int i = 0; i < 4; ++i)
    #pragma unroll
    for (int j = 0; j < 4; ++j)
      pp[(ty * 4 + i) * E_NUM + tx * 4 + j] = acc[i][j];
}

// ---------------- Router top-k: sum partials -> top8 -> renorm -------------
__global__ __launch_bounds__(256) void router_topk(const float* __restrict__ part,
                                                   int* __restrict__ topi,
                                                   float* __restrict__ topw) {
  const int t = blockIdx.x * 4 + (threadIdx.x >> 6);
  const int l = threadIdx.x & 63;
  float myv = part[(size_t)t * E_NUM + l] +
              part[((size_t)N_TOK + t) * E_NUM + l] +
              part[((size_t)2 * N_TOK + t) * E_NUM + l];
  float topv[TOPK]; int topx[TOPK];
  #pragma unroll
  for (int k = 0; k < TOPK; ++k) {
    float bv = myv; int bi = l;
    #pragma unroll
    for (int off = 32; off > 0; off >>= 1) {
      float ov = __shfl_xor(bv, off, 64);
      int oi = __shfl_xor(bi, off, 64);
      if (ov > bv || (ov == bv && oi < bi)) { bv = ov; bi = oi; }
    }
    topv[k] = bv; topx[k] = bi;
    if (l == bi) myv = -INFINITY;
  }
  if (l == 0) {
    float mx = topv[0], w[TOPK], s = 0.f;
    #pragma unroll
    for (int k = 0; k < TOPK; ++k) { w[k] = __expf(topv[k] - mx); s += w[k]; }
    float inv = 1.f / s;
    #pragma unroll
    for (int k = 0; k < TOPK; ++k) {
      topi[t * TOPK + k] = topx[k];
      topw[t * TOPK + k] = w[k] * inv;
    }
  }
}

// ---------------- Histogram (LDS atomics) + prefix, single block -----------
__global__ __launch_bounds__(256) void hist_prefix_kernel(const int* __restrict__ topi,
                                                          int* __restrict__ offsets) {
  __shared__ int h[E_NUM];
  const int tid = threadIdx.x;
  if (tid < E_NUM) h[tid] = 0;
  __syncthreads();
  for (int i = tid; i < NPAIR; i += 256) atomicAdd(&h[topi[i]], 1);
  __syncthreads();
  if (tid == 0) {
    int s = 0;
    for (int e = 0; e < E_NUM; ++e) { offsets[e] = s; s += h[e]; }
    offsets[E_NUM] = s;
  }
}

// ---------------- Scatter: one block per expert, ordered ballot compaction -
__global__ __launch_bounds__(256) void scatter64(const int* __restrict__ topi,
                                                 const float* __restrict__ topw,
                                                 const int* __restrict__ offsets,
                                                 int* __restrict__ toklist,
                                                 float* __restrict__ wlist,
                                                 int* __restrict__ pairpos) {
  const int e = blockIdx.x;
  const int tid = threadIdx.x, l = tid & 63, w = tid >> 6;
  __shared__ int wcnt[4];
  __shared__ int base;
  if (tid == 0) base = offsets[e];
  __syncthreads();
  for (int c = 0; c < NPAIR; c += 256) {
    const int idx = c + tid;
    const bool p = (topi[idx] == e);
    const unsigned long long m = __ballot(p);
    if (l == 0) wcnt[w] = __popcll(m);
    __syncthreads();
    int off = base;
    for (int ww = 0; ww < 4; ++ww)
      if (ww < w) off += wcnt[ww];
    if (p) {
      const int pos = off + __popcll(m & ((1ull << l) - 1ull));
      toklist[pos] = idx >> 3;
      wlist[pos] = topw[idx];
      pairpos[idx] = pos;
    }
    __syncthreads();
    if (tid == 0) base += wcnt[0] + wcnt[1] + wcnt[2] + wcnt[3];
    __syncthreads();
  }
}

// ---------------- K1: gate/up MFMA + SwiGLU -> hmid ------------------------
// 2-phase reg-staged prefetch (T14): issue chunk n+1 global loads before
// chunk n's MFMA phase; write regs->LDS after the barrier.
#define K1_TB 256
#define KC1 64
#define XS_S 72
__global__ __launch_bounds__(512) void k1_gateup(const ushort* __restrict__ xbf,
                                                 const float* __restrict__ wg,
                                                 const float* __restrict__ wu,
                                                 const int* __restrict__ offsets,
                                                 const int* __restrict__ toklist,
                                                 ushort* __restrict__ hmid) {
  const int e = blockIdx.y, ib = blockIdx.x;
  const int i0 = ib * 32;
  const int start = offsets[e], cnt = offsets[e + 1] - start;
  const int tokbase = blockIdx.z * K1_TB;
  if (tokbase >= cnt) return;
  const int cntb = min(K1_TB, cnt - tokbase);
  const int ntiles = (cntb + 127) >> 7;

  __shared__ __align__(16) char smem[47104];
  ushort* xs = (ushort*)smem;                 // [256][XS_S]  36864 B
  ushort* Bs = (ushort*)(smem + 36864);       // [64][XS_S]   9216 B
  int*    tks = (int*)(smem + 46080);         // [256]
  float*  gbuf = (float*)smem;                // epilogue overlay
  ushort* hbuf = (ushort*)(smem + 16384);     // epilogue overlay

  const int tid = threadIdx.x;
  if (tid < K1_TB)
    tks[tid] = toklist[start + tokbase + min(tid, cntb - 1)];
  __syncthreads();

  const int l = tid & 63, wid = tid >> 6;
  const int tf = wid & 3, guw = wid >> 2;

  // staging roles
  const int xrow = tid >> 3, xcol8 = tid & 7;          // x: 64 rows per it-step? no: row=u>>3
  const int sq = tid & 15, sm = tid >> 4;
  const int scol = (sq >> 3) * 32 + (sq & 7) * 4;
  const float* sbase = (sq < 8 ? wg : wu) + (size_t)e * H_DIM * I_DIM + i0 + (sq & 7) * 4;

  f32x4 acc[2][2][2] = {};
  const int ko = (l >> 4) * 8;

  // prefetch chunk 0 into regs
  short8 xr[4];
  float4 bv0, bv1;
  {
    #pragma unroll
    for (int it = 0; it < 4; ++it) {
      const int u = tid + it * 512;
      const int row = u >> 3, col8 = u & 7;
      xr[it] = *(const short8*)(xbf + (size_t)tks[row] * H_DIM + 0 + col8 * 8);
    }
    const int k0 = 2 * sm;
    bv0 = *(const float4*)(sbase + (size_t)k0 * I_DIM);
    bv1 = *(const float4*)(sbase + (size_t)(k0 + 1) * I_DIM);
  }

  for (int kh = 0; kh < H_DIM; kh += KC1) {
    __syncthreads();  // previous chunk's LDS reads complete
    // write staged regs -> LDS
    #pragma unroll
    for (int it = 0; it < 4; ++it) {
      const int u = tid + it * 512;
      const int row = u >> 3, col8 = u & 7;
      *(short8*)&xs[row * XS_S + col8 * 8] = xr[it];
    }
    {
      const int k0 = 2 * sm;
      *(unsigned*)&Bs[(scol + 0) * XS_S + k0] = pack2(bv0.x, bv1.x);
      *(unsigned*)&Bs[(scol + 1) * XS_S + k0] = pack2(bv0.y, bv1.y);
      *(unsigned*)&Bs[(scol + 2) * XS_S + k0] = pack2(bv0.z, bv1.z);
      *(unsigned*)&Bs[(scol + 3) * XS_S + k0] = pack2(bv0.w, bv1.w);
    }
    // issue next chunk's loads (fly during MFMA phase)
    const int khn = kh + KC1;
    if (khn < H_DIM) {
      #pragma unroll
      for (int it = 0; it < 4; ++it) {
        const int u = tid + it * 512;
        const int row = u >> 3, col8 = u & 7;
        xr[it] = *(const short8*)(xbf + (size_t)tks[row] * H_DIM + khn + col8 * 8);
      }
      const int k0 = 2 * sm;
      bv0 = *(const float4*)(sbase + (size_t)(khn + k0) * I_DIM);
      bv1 = *(const float4*)(sbase + (size_t)(khn + k0 + 1) * I_DIM);
    }
    __syncthreads();
    #pragma unroll
    for (int ks = 0; ks < KC1 / 32; ++ks) {
      const int kofs = ks * 32 + ko;
      short8 b0 = *(const short8*)&Bs[(guw * 32 + (l & 15)) * XS_S + kofs];
      short8 b1 = *(const short8*)&Bs[(guw * 32 + 16 + (l & 15)) * XS_S + kofs];
      #pragma unroll
      for (int tile = 0; tile < 2; ++tile) {
        if (tile < ntiles) {
          short8 a0 = *(const short8*)&xs[(tile * 128 + tf * 32 + (l & 15)) * XS_S + kofs];
          short8 a1 = *(const short8*)&xs[(tile * 128 + tf * 32 + 16 + (l & 15)) * XS_S + kofs];
          acc[tile][0][0] = mfma16(a0, b0, acc[tile][0][0]);
          acc[tile][1][0] = mfma16(a1, b0, acc[tile][1][0]);
          acc[tile][0][1] = mfma16(a0, b1, acc[tile][0][1]);
          acc[tile][1][1] = mfma16(a1, b1, acc[tile][1][1]);
        }
      }
    }
  }

  // epilogue: SwiGLU exchange gate<->up waves, then store hmid
  const int rgrp = l >> 4, col_l = l & 15;
  #pragma unroll
  for (int tile = 0; tile < 2; ++tile) {
    if (tile >= ntiles) break;
    const int tm = min(128, cntb - tile * 128);
    __syncthreads();
    if (guw == 0) {
      #pragma unroll
      for (int tr = 0; tr < 2; ++tr)
        #pragma unroll
        for (int cf = 0; cf < 2; ++cf)
          #pragma unroll
          for (int j = 0; j < 4; ++j) {
            int row = tr * 16 + rgrp * 4 + j, col = cf * 16 + col_l;
            gbuf[tf * 1024 + row * 32 + col] = acc[tile][tr][cf][j];
          }
    }
    __syncthreads();
    if (guw == 1) {
      #pragma unroll
      for (int tr = 0; tr < 2; ++tr)
        #pragma unroll
        for (int cf = 0; cf < 2; ++cf)
          #pragma unroll
          for (int j = 0; j < 4; ++j) {
            int row = tr * 16 + rgrp * 4 + j, col = cf * 16 + col_l;
            float g = gbuf[tf * 1024 + row * 32 + col];
            float hm = g / (1.f + __expf(-g)) * acc[tile][tr][cf][j];
            hbuf[(tf * 32 + row) * 32 + col] = f2bf(hm);
          }
    }
    __syncthreads();
    {
      const int row = tid >> 2, part = tid & 3;
      if (row < tm) {
        ushort* dst = hmid + (size_t)(start + tokbase + tile * 128 + row) * I_DIM + i0 + part * 8;
        *(short8*)dst = *(const short8*)&hbuf[row * 32 + part * 8];
      }
    }
  }
}

// ---------------- K2 (fast): down-proj MFMA -> out_pairs (no atomics) ------
#define KC2 128
#define DS_S 136
__global__ __launch_bounds__(512) void k2_down_pairs(const ushort* __restrict__ hmid,
                                                     const float* __restrict__ wd,
                                                     const int* __restrict__ offsets,
                                                     float* __restrict__ out_pairs) {
  const int e = blockIdx.y, hs = blockIdx.x;
  const int h0 = hs * 192;
  const int start = offsets[e], cnt = offsets[e + 1] - start;
  const int tokbase = blockIdx.z * 128;
  if (tokbase >= cnt) return;
  const int tm = min(128, cnt - tokbase);

  __shared__ ushort Ds[192][DS_S];

  const int tid = threadIdx.x;
  const int l = tid & 63, wid = tid >> 6;
  const int tf = wid & 3, ch = wid >> 2;
  f32x4 acc[2][6] = {};

  const int p0 = min(start + tokbase + tf * 32 + (l & 15), NPAIR - 1);
  const int p1 = min(start + tokbase + tf * 32 + 16 + (l & 15), NPAIR - 1);
  const int ko = (l >> 4) * 8;

  const float* wde = wd + (size_t)e * I_DIM * H_DIM;

  for (int kh = 0; kh < I_DIM; kh += KC2) {
    __syncthreads();
    #pragma unroll
    for (int it = 0; it < 6; ++it) {
      int idx = tid + it * 512;
      int q = idx % 48, m = idx / 48;
      const int k0 = 2 * m;
      const float* src = wde + (size_t)(kh + k0) * H_DIM + h0 + q * 4;
      float4 v0 = *(const float4*)src;
      float4 v1 = *(const float4*)(src + H_DIM);
      *(unsigned*)&Ds[q * 4 + 0][k0] = pack2(v0.x, v1.x);
      *(unsigned*)&Ds[q * 4 + 1][k0] = pack2(v0.y, v1.y);
      *(unsigned*)&Ds[q * 4 + 2][k0] = pack2(v0.z, v1.z);
      *(unsigned*)&Ds[q * 4 + 3][k0] = pack2(v0.w, v1.w);
    }
    __syncthreads();
    const ushort* ap0 = hmid + (size_t)p0 * I_DIM + kh;
    const ushort* ap1 = hmid + (size_t)p1 * I_DIM + kh;
    #pragma unroll
    for (int ks = 0; ks < KC2 / 32; ++ks) {
      short8 a0 = *(const short8*)(ap0 + ks * 32 + ko);
      short8 a1 = *(const short8*)(ap1 + ks * 32 + ko);
      #pragma unroll
      for (int cf = 0; cf < 6; ++cf) {
        short8 b = *(const short8*)&Ds[ch * 96 + cf * 16 + (l & 15)][ks * 32 + ko];
        acc[0][cf] = mfma16(a0, b, acc[0][cf]);
        acc[1][cf] = mfma16(a1, b, acc[1][cf]);
      }
    }
  }

  const int rgrp = l >> 4, col_l = l & 15;
  #pragma unroll
  for (int tr = 0; tr < 2; ++tr)
    #pragma unroll
    for (int j = 0; j < 4; ++j) {
      int r = tf * 32 + tr * 16 + rgrp * 4 + j;
      if (r < tm) {
        const size_t prow = (size_t)(start + tokbase + r);
        #pragma unroll
        for (int cf = 0; cf < 6; ++cf) {
          int hcol = h0 + ch * 96 + cf * 16 + col_l;
          out_pairs[prow * H_DIM + hcol] = acc[tr][cf][j];
        }
      }
    }
}

// ---------------- K2 (fallback): atomic accumulate (round-6 path) ----------
__global__ __launch_bounds__(512) void k2_down_atomic(const ushort* __restrict__ hmid,
                                                      const float* __restrict__ wd,
                                                      const int* __restrict__ offsets,
                                                      const int* __restrict__ toklist,
                                                      const float* __restrict__ wlist,
                                                      float* __restrict__ out) {
  const int e = blockIdx.y, hs = blockIdx.x;
  const int h0 = hs * 192;
  const int start = offsets[e], cnt = offsets[e + 1] - start;
  const int tokbase = blockIdx.z * 128;
  if (tokbase >= cnt) return;
  const int tm = min(128, cnt - tokbase);

  __shared__ ushort Ds[192][DS_S];
  __shared__ float sws[128];
  __shared__ int tks[128];

  const int tid = threadIdx.x;
  if (tid < 128) {
    int p = start + tokbase + min(tid, tm - 1);
    sws[tid] = (tid < tm) ? wlist[p] : 0.f;
    tks[tid] = toklist[p];
  }

  const int l = tid & 63, wid = tid >> 6;
  const int tf = wid & 3, ch = wid >> 2;
  f32x4 acc[2][6] = {};

  const int p0 = min(start + tokbase + tf * 32 + (l & 15), NPAIR - 1);
  const int p1 = min(start + tokbase + tf * 32 + 16 + (l & 15), NPAIR - 1);
  const int ko = (l >> 4) * 8;

  const float* wde = wd + (size_t)e * I_DIM * H_DIM;

  for (int kh = 0; kh < I_DIM; kh += KC2) {
    __syncthreads();
    #pragma unroll
    for (int it = 0; it < 6; ++it) {
      int idx = tid + it * 512;
      int q = idx % 48, m = idx / 48;
      const int k0 = 2 * m;
      const float* src = wde + (size_t)(kh + k0) * H_DIM + h0 + q * 4;
      float4 v0 = *(const float4*)src;
      float4 v1 = *(const float4*)(src + H_DIM);
      *(unsigned*)&Ds[q * 4 + 0][k0] = pack2(v0.x, v1.x);
      *(unsigned*)&Ds[q * 4 + 1][k0] = pack2(v0.y, v1.y);
      *(unsigned*)&Ds[q * 4 + 2][k0] = pack2(v0.z, v1.z);
      *(unsigned*)&Ds[q * 4 + 3][k0] = pack2(v0.w, v1.w);
    }
    __syncthreads();
    const ushort* ap0 = hmid + (size_t)p0 * I_DIM + kh;
    const ushort* ap1 = hmid + (size_t)p1 * I_DIM + kh;
    #pragma unroll
    for (int ks = 0; ks < KC2 / 32; ++ks) {
      short8 a0 = *(const short8*)(ap0 + ks * 32 + ko);
      short8 a1 = *(const short8*)(ap1 + ks * 32 + ko);
      #pragma unroll
      for (int cf = 0; cf < 6; ++cf) {
        short8 b = *(const short8*)&Ds[ch * 96 + cf * 16 + (l & 15)][ks * 32 + ko];
        acc[0][cf] = mfma16(a0, b, acc[0][cf]);
        acc[1][cf] = mfma16(a1, b, acc[1][cf]);
      }
    }
  }

  const int rgrp = l >> 4, col_l = l & 15;
  #pragma unroll
  for (int tr = 0; tr < 2; ++tr)
    #pragma unroll
    for (int j = 0; j < 4; ++j) {
      int r = tf * 32 + tr * 16 + rgrp * 4 + j;
      if (r < tm) {
        float w = sws[r];
        int trow = tks[r];
        #pragma unroll
        for (int cf = 0; cf < 6; ++cf) {
          int hcol = h0 + ch * 96 + cf * 16 + col_l;
          atomicAdd(&out[(size_t)trow * H_DIM + hcol], acc[tr][cf][j] * w);
        }
      }
    }
}

// ---------------- Gather-reduce: out[t] = sum_k w_k * out_pairs[pos(t,k)] --
__global__ __launch_bounds__(192) void moe_reduce(const float* __restrict__ out_pairs,
                                                  const int* __restrict__ pairpos,
                                                  const float* __restrict__ topw,
                                                  float* __restrict__ out) {
  const int t = blockIdx.x;
  const int c = threadIdx.x;  // 0..191, float4 column group
  float4 acc = make_float4(0.f, 0.f, 0.f, 0.f);
  #pragma unroll
  for (int k = 0; k < TOPK; ++k) {
    const int pos = pairpos[t * TOPK + k];
    const float w = topw[t * TOPK + k];
    float4 v = *(const float4*)&out_pairs[(size_t)pos * H_DIM + c * 4];
    acc.x = fmaf(w, v.x, acc.x);
    acc.y = fmaf(w, v.y, acc.y);
    acc.z = fmaf(w, v.z, acc.z);
    acc.w = fmaf(w, v.w, acc.w);
  }
  *(float4*)&out[(size_t)t * H_DIM + c * 4] = acc;
}

extern "C" void kernel_launch(void* const* d_in, const int* in_sizes, int n_in,
                              void* d_out, int out_size, void* d_ws, size_t ws_size,
                              hipStream_t stream) {
  const float* x  = (const float*)d_in[0];
  const float* rw = (const float*)d_in[1];
  const float* wg = (const float*)d_in[2];
  const float* wu = (const float*)d_in[3];
  const float* wd = (const float*)d_in[4];
  float* out = (float*)d_out;

  char* ws = (char*)d_ws;
  int*    topi     = (int*)(ws + 0);          // 64 KB
  float*  topw     = (float*)(ws + 65536);    // 64 KB
  int*    offsets  = (int*)(ws + 131072);     // 260 B
  int*    toklist  = (int*)(ws + 132608);     // 64 KB
  float*  wlist    = (float*)(ws + 198144);   // 64 KB
  int*    pairpos  = (int*)(ws + 264192);     // 64 KB
  ushort* xbf      = (ushort*)(ws + 331776);  // 3 MB
  ushort* hmid     = (ushort*)(ws + 3477504); // 8 MB
  float*  rpart    = (float*)(ws + 3477504);  // overlaps hmid; dead before k1
  float*  out_pairs= (float*)(ws + 11866112); // 50.3 MB (fast path only)
  const bool fast = ws_size >= 62197760ull;

  cvt_x_kernel<<<(N_TOK * H_DIM / 8) / 512, 512, 0, stream>>>(x, xbf);
  router_gemm<<<dim3(N_TOK / 64, 3), 256, 0, stream>>>(x, rw, rpart);
  router_topk<<<N_TOK / 4, 256, 0, stream>>>(rpart, topi, topw);
  hist_prefix_kernel<<<1, 256, 0, stream>>>(topi, offsets);
  scatter64<<<E_NUM, 256, 0, stream>>>(topi, topw, offsets, toklist, wlist, pairpos);
  k1_gateup<<<dim3(8, E_NUM, N_TOK / K1_TB), 512, 0, stream>>>(
      xbf, wg, wu, offsets, toklist, hmid);
  if (fast) {
    k2_down_pairs<<<dim3(4, E_NUM, N_TOK / 128), 512, 0, stream>>>(
        hmid, wd, offsets, out_pairs);
    moe_reduce<<<N_TOK, 192, 0, stream>>>(out_pairs, pairpos, topw, out);
  } else {
    hipMemsetAsync(d_out, 0, (size_t)out_size * sizeof(float), stream);
    k2_down_atomic<<<dim3(4, E_NUM, N_TOK / 128), 512, 0, stream>>>(
        hmid, wd, offsets, toklist, wlist, out);
  }
}